// Round 25
// baseline (289.538 us; speedup 1.0000x reference)
//
#include <hip/hip_runtime.h>
#include <hip/hip_bf16.h>

#define NN 50000
#define EE 800000
#define DIN 1433
#define KTOT 1432
#define KHALF 716
#define NKT 23          // ceil(716/32) k-tiles per half
#define NB 196          // ceil(50000/256)
#define EPSC 1e-7f
#define MINN 1e-15f
#define MAXN 1e6f

typedef __attribute__((ext_vector_type(8))) short bf16x8;
typedef __attribute__((ext_vector_type(4))) float f32x4;

// ---- workspace layout (float offsets) ----
#define WF_OFF     0                          // 94208 floats
#define Z1A_OFF    94208                      // 50000*64 f32
#define Z1B_OFF    (Z1A_OFF + 3200000)        // 50000*64 f32
#define XTB_OFF    (Z1B_OFF + 3200000)        // 50000*64 bf16 = 1600000 floats
#define XT3_OFF    (XTB_OFF + 1600000)        // 50000*8 f32
#define CNT_OFF    (XT3_OFF + 400000)
#define ROWPTR_OFF (CNT_OFF + 50000)          // 50002 (padded)
#define CUR_OFF    (ROWPTR_OFF + 50002)
#define BSUM_OFF   (CUR_OFF + 50000)          // 256
#define UB_OFF     (BSUM_OFF + 256)           // 128
#define EP_OFF     (UB_OFF + 128)             // 800000 uint2

__device__ __forceinline__ float wsum(float v) {
#pragma unroll
  for (int o = 1; o < 64; o <<= 1) v += __shfl_xor(v, o, 64);
  return v;
}

__device__ __forceinline__ float gsum8(float v) {
#pragma unroll
  for (int o = 1; o < 8; o <<= 1) v += __shfl_xor(v, o, 64);
  return v;
}

__device__ __forceinline__ void split_bf(float v, unsigned int& hbits16, unsigned int& lbits16) {
  unsigned int b = __float_as_uint(v);
  unsigned int hb = b & 0xFFFF0000u;
  float r = v - __uint_as_float(hb);
  unsigned int lb = __float_as_uint(r);
  lbits16 = (lb + 0x7FFFu + ((lb >> 16) & 1u)) >> 16;
  hbits16 = hb >> 16;
}

__device__ __forceinline__ unsigned short f2bf_rne(float v) {
  unsigned int b = __float_as_uint(v);
  return (unsigned short)((b + 0x7FFFu + ((b >> 16) & 1u)) >> 16);
}
__device__ __forceinline__ float bf2f(unsigned short u) {
  return __uint_as_float(((unsigned int)u) << 16);
}

// ---- fast transcendentals (validated R8) ----
__device__ __forceinline__ float fsinh(float x) {
  float e = __expf(x);
  return 0.5f * (e - __fdividef(1.f, e));
}
__device__ __forceinline__ float facoshp(float z) {
  return __logf(z + sqrtf(fmaxf(z * z - 1.f, 0.f)));
}

// ===================== node-chain math (fast-math, validated R8) ==============
__device__ float bias_tangent(const float* b, int lane, int D) {
  const bool sp = (lane >= 1) && (lane < D);
  float bsp = sp ? b[lane] : 0.f;
  float rb = fmaxf(sqrtf(wsum(bsp * bsp)), MINN);
  float bsh = fsinh(rb);
  float hb = sp ? bsh * __fdividef(bsp, rb) : 0.f;
  float hbn2 = wsum(hb * hb);
  float hb0 = sqrtf(fmaxf(1.f + hbn2, EPSC));
  float hbyn = fmaxf(sqrtf(hbn2), MINN);
  return sp ? facoshp(fmaxf(hb0, 1.f + EPSC)) * __fdividef(hb, hbyn) : 0.f;
}

__device__ float chain_with_u(float z, float u, int lane, int D) {
  const bool sp = (lane >= 1) && (lane < D);
  float s = sp ? z : 0.f;
  float r = fmaxf(sqrtf(wsum(s * s)), MINN);
  float sh = fsinh(r);
  float y = sp ? sh * __fdividef(s, r) : 0.f;
  float yn2 = wsum(y * y);
  float x0 = sqrtf(fmaxf(1.f + yn2, EPSC));
  float y_norm = fmaxf(sqrtf(yn2), MINN);
  float ynv = sp ? __fdividef(y, y_norm) : 0.f;
  float alpha = wsum(ynv * u);
  float wsp = sp ? u - alpha * (1.f - x0) * ynv : 0.f;
  float ux = wsum(y * wsp);
  float v0 = __fdividef(ux, fmaxf(x0, EPSC));
  float vt = (lane == 0) ? v0 : wsp;
  float md = wsum(vt * vt) - 2.f * v0 * v0;
  float nu = sqrtf(fmaxf(md, EPSC));
  nu = fminf(nu, MAXN);
  float th = fmaxf(nu, MINN);
  float e = __expf(th), ei = __fdividef(1.f, e);
  float cth = 0.5f * (e + ei), sth = 0.5f * (e - ei);
  float resx = (lane == 0) ? x0 : y;
  float eres = fmaf(cth, resx, sth * __fdividef(vt, th));
  float en2 = wsum(sp ? eres * eres : 0.f);
  float e0 = sqrtf(fmaxf(1.f + en2, EPSC));
  float eyn = fmaxf(sqrtf(en2), MINN);
  return sp ? facoshp(fmaxf(e0, 1.f + EPSC)) * __fdividef(eres, eyn) : 0.f;
}

__device__ float agg_act_chain(float sin_, int lane, int D) {
  const bool sp = (lane >= 1) && (lane < D);
  float s = sp ? sin_ : 0.f;
  float r = fmaxf(sqrtf(wsum(s * s)), MINN);
  float sh = fsinh(r);
  float g = sp ? sh * __fdividef(s, r) : 0.f;
  float gn2 = wsum(g * g);
  float g0 = sqrtf(fmaxf(1.f + gn2, EPSC));
  float gyn = fmaxf(sqrtf(gn2), MINN);
  float l = sp ? facoshp(fmaxf(g0, 1.f + EPSC)) * __fdividef(g, gyn) : 0.f;
  float t = fmaxf(l, 0.f);
  float rt = fmaxf(sqrtf(wsum(t * t)), MINN);
  float sht = fsinh(rt);
  float h = sp ? sht * __fdividef(t, rt) : 0.f;
  float hn2 = wsum(h * h);
  float h0 = sqrtf(fmaxf(1.f + hn2, EPSC));
  float hyn = fmaxf(sqrtf(hn2), MINN);
  return sp ? facoshp(fmaxf(h0, 1.f + EPSC)) * __fdividef(h, hyn) : 0.f;
}

__device__ float agg_act_chain8(float sin_, int f) {
  const bool sp = (f >= 1) && (f < 7);
  float s = sp ? sin_ : 0.f;
  float r = fmaxf(sqrtf(gsum8(s * s)), MINN);
  float sh = fsinh(r);
  float g = sp ? sh * __fdividef(s, r) : 0.f;
  float gn2 = gsum8(g * g);
  float g0 = sqrtf(fmaxf(1.f + gn2, EPSC));
  float gyn = fmaxf(sqrtf(gn2), MINN);
  float l = sp ? facoshp(fmaxf(g0, 1.f + EPSC)) * __fdividef(g, gyn) : 0.f;
  float t = fmaxf(l, 0.f);
  float rt = fmaxf(sqrtf(gsum8(t * t)), MINN);
  float sht = fsinh(rt);
  float h = sp ? sht * __fdividef(t, rt) : 0.f;
  float hn2 = gsum8(h * h);
  float h0 = sqrtf(fmaxf(1.f + hn2, EPSC));
  float hyn = fmaxf(sqrtf(hn2), MINN);
  return sp ? facoshp(fmaxf(h0, 1.f + EPSC)) * __fdividef(h, hyn) : 0.f;
}

// ===== prep: W1 fragments (0..91) + bias tangents (92) + cnt zero (93..288) ===
__global__ __launch_bounds__(256) void prep_wb_zero(const float* __restrict__ W1,
                                                    const float* __restrict__ b1,
                                                    const float* __restrict__ b2,
                                                    unsigned short* __restrict__ wfrag,
                                                    float* __restrict__ ub,
                                                    int* __restrict__ cnt) {
  if (blockIdx.x >= 93) {
    int i = (blockIdx.x - 93) * 256 + threadIdx.x;
    if (i < NN) cnt[i] = 0;
    return;
  }
  if (blockIdx.x == 92) {
    const int w = threadIdx.x >> 6, lane = threadIdx.x & 63;
    if (w == 0) ub[lane] = bias_tangent(b1, lane, 64);
    else if (w == 1) ub[64 + lane] = bias_tangent(b2, lane, 7);
    return;
  }
  int idx = blockIdx.x * 256 + threadIdx.x;
  int lane = idx & 63;
  int c = (idx >> 6) & 7;
  int rest = idx >> 9;
  int kt = rest % NKT;
  int half = rest / NKT;
  int type = c >> 2, nt = c & 3;
  int col = nt * 16 + (lane & 15);
  unsigned short vals[8];
#pragma unroll
  for (int i = 0; i < 8; ++i) {
    int lk = kt * 32 + (lane >> 4) * 8 + i;
    float wv = (lk < KHALF) ? W1[col * DIN + half * KHALF + lk + 1] : 0.f;
    unsigned int h16, l16;
    split_bf(wv, h16, l16);
    vals[i] = (unsigned short)((type == 0) ? h16 : l16);
  }
  unsigned short* dst = wfrag + (((size_t)(half * NKT + kt) * 8 + c) * 64 + lane) * 8;
#pragma unroll
  for (int i = 0; i < 8; ++i) dst[i] = vals[i];
}

// ===================== CSR mid-chain ==========================================
__global__ __launch_bounds__(256) void k_blocksum(const int* __restrict__ cnt,
                                                  int* __restrict__ bsum) {
  __shared__ int wpart[4];
  int i = blockIdx.x * 256 + threadIdx.x;
  int v = (i < NN) ? cnt[i] : 0;
  int s = v;
#pragma unroll
  for (int o = 1; o < 64; o <<= 1) s += __shfl_xor(s, o, 64);
  if ((threadIdx.x & 63) == 0) wpart[threadIdx.x >> 6] = s;
  __syncthreads();
  if (threadIdx.x == 0) bsum[blockIdx.x] = wpart[0] + wpart[1] + wpart[2] + wpart[3];
}

// scanb fused into apply (parallel redundant scan; validated R23)
__global__ __launch_bounds__(256) void k_scan_apply(const int* __restrict__ cnt,
                                                    const int* __restrict__ bsum,
                                                    int* __restrict__ rowptr,
                                                    int* __restrict__ cur) {
  __shared__ int s[256];
  __shared__ int base_sh;
  const int t = threadIdx.x;
  const int b = blockIdx.x;
  int bv = (t < NB) ? bsum[t] : 0;
  s[t] = bv;
  __syncthreads();
  for (int o = 1; o < 256; o <<= 1) {
    int a = (t >= o) ? s[t - o] : 0;
    __syncthreads();
    s[t] += a;
    __syncthreads();
  }
  if (t == b) base_sh = s[b] - bv;
  __syncthreads();
  const int base = base_sh;
  __syncthreads();
  int i = b * 256 + t;
  int v = (i < NN) ? cnt[i] : 0;
  s[t] = v;
  __syncthreads();
  for (int o = 1; o < 256; o <<= 1) {
    int a = (t >= o) ? s[t - o] : 0;
    __syncthreads();
    s[t] += a;
    __syncthreads();
  }
  int ex = s[t] - v + base;
  if (i < NN) { rowptr[i] = ex; cur[i] = ex; }
  if (i == NN - 1) rowptr[NN] = EE;
}

// ======== GEMM1 half (R16 pipeline) + hist plane (blockIdx.y==2) ==============
__global__ __launch_bounds__(256) void gemm_hist(const float* __restrict__ x,
                                                 const unsigned short* __restrict__ wfrag,
                                                 float* __restrict__ z,
                                                 const int* __restrict__ row,
                                                 int* __restrict__ cnt) {
  if (blockIdx.y == 2) {   // histogram plane: 1563 blocks x 512 edges
    int e = blockIdx.x * 512 + threadIdx.x;
    if (e < EE) atomicAdd(&cnt[row[e]], 1);
    e += 256;
    if (e < EE) atomicAdd(&cnt[row[e]], 1);
    return;
  }
  __shared__ __align__(16) float XA[3 * 1024];               // 12 KB
  __shared__ __align__(16) unsigned short BB[2][8][64][8];   // 16 KB
  const int tid = threadIdx.x;
  const int w = tid >> 6, lane = tid & 63;
  const int row0 = blockIdx.x * 32;
  const int half = blockIdx.y;
  const unsigned short* wf = wfrag + (size_t)half * NKT * 4096;
  float* zp = z + (size_t)half * 3200000;
  const int nt0 = (w >> 1) * 2;

  auto stageB = [&](int kt, int p) {
    const unsigned short* src = wf + (size_t)kt * 4096 + (2 * w) * 512 + lane * 8;
    __builtin_amdgcn_global_load_lds(
        (const __attribute__((address_space(1))) unsigned int*)src,
        (__attribute__((address_space(3))) unsigned int*)(&BB[p][2 * w][0][0]), 16, 0, 0);
    __builtin_amdgcn_global_load_lds(
        (const __attribute__((address_space(1))) unsigned int*)(src + 512),
        (__attribute__((address_space(3))) unsigned int*)(&BB[p][2 * w + 1][0][0]), 16, 0, 0);
  };
  auto stageA = [&](int kt, int q) {
    const int r = w * 8 + (lane >> 3);
    const int lb = (lane & 7) ^ (r & 7);
    int grow = row0 + r; if (grow >= NN) grow = NN - 1;
    size_t off = (size_t)grow * DIN + 1 + half * KHALF + kt * 32 + lb * 4;
    if (off > (size_t)NN * DIN - 4) off = (size_t)NN * DIN - 4;   // tail clamp
    __builtin_amdgcn_global_load_lds(
        (const __attribute__((address_space(1))) unsigned int*)(x + off),
        (__attribute__((address_space(3))) unsigned int*)(XA + q * 1024 + w * 256),
        16, 0, 0);
  };

  f32x4 acc[2];
  acc[0] = (f32x4){0.f, 0.f, 0.f, 0.f};
  acc[1] = (f32x4){0.f, 0.f, 0.f, 0.f};

  stageB(0, 0);
  stageA(0, 0);
  stageA(1, 1);
  __builtin_amdgcn_sched_barrier(0);
  asm volatile("s_waitcnt vmcnt(1)" ::: "memory");
  __builtin_amdgcn_s_barrier();
  __builtin_amdgcn_sched_barrier(0);

  const int rr = (w & 1) * 16 + (lane & 15);
  const int b0 = (lane >> 4) * 2;
  const int pb0 = (b0 ^ (rr & 7)) * 4;
  const int pb1 = ((b0 + 1) ^ (rr & 7)) * 4;

  for (int kt = 0; kt < NKT; ++kt) {
    if (kt + 1 < NKT) stageB(kt + 1, (kt + 1) & 1);
    if (kt + 2 < NKT) stageA(kt + 2, (kt + 2) % 3);
    const float* xa = XA + (kt % 3) * 1024 + rr * 32;
    float4 f0 = *(const float4*)(xa + pb0);
    float4 f1 = *(const float4*)(xa + pb1);
    float af[8] = {f0.x, f0.y, f0.z, f0.w, f1.x, f1.y, f1.z, f1.w};
    unsigned int h[8], l[8];
#pragma unroll
    for (int j = 0; j < 8; ++j) split_bf(af[j], h[j], l[j]);
    bf16x8 ah, al;
#pragma unroll
    for (int j = 0; j < 8; ++j) { ah[j] = (short)h[j]; al[j] = (short)l[j]; }
    bf16x8 bh[2], bl[2];
#pragma unroll
    for (int n = 0; n < 2; ++n) {
      bh[n] = *(const bf16x8*)&BB[kt & 1][nt0 + n][lane][0];
      bl[n] = *(const bf16x8*)&BB[kt & 1][4 + nt0 + n][lane][0];
    }
    __builtin_amdgcn_s_setprio(1);
#pragma unroll
    for (int n = 0; n < 2; ++n) {
      acc[n] = __builtin_amdgcn_mfma_f32_16x16x32_bf16(ah, bh[n], acc[n], 0, 0, 0);
      acc[n] = __builtin_amdgcn_mfma_f32_16x16x32_bf16(ah, bl[n], acc[n], 0, 0, 0);
      acc[n] = __builtin_amdgcn_mfma_f32_16x16x32_bf16(al, bh[n], acc[n], 0, 0, 0);
    }
    __builtin_amdgcn_s_setprio(0);
    if (kt + 1 < NKT) {
      __builtin_amdgcn_sched_barrier(0);
      asm volatile("s_waitcnt lgkmcnt(0)" ::: "memory");
      if (kt + 2 < NKT) asm volatile("s_waitcnt vmcnt(1)" ::: "memory");
      else              asm volatile("s_waitcnt vmcnt(0)" ::: "memory");
      __builtin_amdgcn_s_barrier();
      __builtin_amdgcn_sched_barrier(0);
    }
  }
#pragma unroll
  for (int n = 0; n < 2; ++n)
#pragma unroll
    for (int i = 0; i < 4; ++i) {
      int orow = row0 + (w & 1) * 16 + (lane >> 4) * 4 + i;
      int ocol = (nt0 + n) * 16 + (lane & 15);
      if (orow < NN) zp[(size_t)orow * 64 + ocol] = acc[n][i];
    }
}

// ===== node1 (blocks 0..12499) + scatter plane (blocks 12500..15624) ==========
__global__ __launch_bounds__(256) void node1_scatter(const float* __restrict__ z1a,
                                                     const float* __restrict__ z1b,
                                                     const float* __restrict__ ub,
                                                     unsigned short* __restrict__ xtb,
                                                     const int* __restrict__ row,
                                                     const int* __restrict__ col,
                                                     const float* __restrict__ ew,
                                                     int* __restrict__ cur,
                                                     uint2* __restrict__ ep) {
  if (blockIdx.x >= 12500) {   // scatter plane: 3125 blocks
    int e = (blockIdx.x - 12500) * 256 + threadIdx.x;
    if (e < EE) {
      int p = atomicAdd(&cur[row[e]], 1);
      uint2 q;
      q.x = (unsigned int)col[e];
      q.y = __float_as_uint(ew[e]);
      ep[p] = q;
    }
    return;
  }
  const int node = blockIdx.x * 4 + (threadIdx.x >> 6);
  const int lane = threadIdx.x & 63;
  const int idx = node * 64 + lane;
  float z = z1a[idx] + z1b[idx];
  float u1 = ub[lane];
  float o = chain_with_u(z, u1, lane, 64);
  xtb[idx] = f2bf_rne(o);
}

// ===== agg1: 2 waves/node (interleaved gather batches fly concurrently) =======
// Wave half h takes batches p=s0+h*8, step 16 (masked unroll-8); partials
// combine via LDS; h=0 wave runs the chains. Grid 25000 (2 nodes/block).
__global__ __launch_bounds__(256) void agg1_node2(const int* __restrict__ rowptr,
                                                  const uint2* __restrict__ ep,
                                                  const unsigned short* __restrict__ xtb,
                                                  const float* __restrict__ W2,
                                                  const float* __restrict__ ub,
                                                  float* __restrict__ xt3) {
  __shared__ float part[2][64];
  const int w = threadIdx.x >> 6;        // 0..3
  const int lane = threadIdx.x & 63;
  const int nodeLocal = w >> 1;          // 0,1
  const int h = w & 1;                   // gather half
  const int node = blockIdx.x * 2 + nodeLocal;
  const int s0 = rowptr[node], s1 = rowptr[node + 1];
  float a0 = 0.f, a1 = 0.f, a2 = 0.f, a3 = 0.f;
  float a4 = 0.f, a5 = 0.f, a6 = 0.f, a7 = 0.f;
  for (int p = s0 + h * 8; p < s1; p += 16) {
    int p1 = min(p + 1, s1 - 1), p2 = min(p + 2, s1 - 1), p3 = min(p + 3, s1 - 1);
    int p4 = min(p + 4, s1 - 1), p5 = min(p + 5, s1 - 1), p6 = min(p + 6, s1 - 1), p7 = min(p + 7, s1 - 1);
    uint2 q0 = ep[p], q1 = ep[p1], q2 = ep[p2], q3 = ep[p3];
    uint2 q4 = ep[p4], q5 = ep[p5], q6 = ep[p6], q7 = ep[p7];
    float w0 = __uint_as_float(q0.y);
    float w1 = (p + 1 < s1) ? __uint_as_float(q1.y) : 0.f;
    float w2 = (p + 2 < s1) ? __uint_as_float(q2.y) : 0.f;
    float w3 = (p + 3 < s1) ? __uint_as_float(q3.y) : 0.f;
    float w4 = (p + 4 < s1) ? __uint_as_float(q4.y) : 0.f;
    float w5 = (p + 5 < s1) ? __uint_as_float(q5.y) : 0.f;
    float w6 = (p + 6 < s1) ? __uint_as_float(q6.y) : 0.f;
    float w7 = (p + 7 < s1) ? __uint_as_float(q7.y) : 0.f;
    a0 = fmaf(w0, bf2f(xtb[(size_t)q0.x * 64 + lane]), a0);
    a1 = fmaf(w1, bf2f(xtb[(size_t)q1.x * 64 + lane]), a1);
    a2 = fmaf(w2, bf2f(xtb[(size_t)q2.x * 64 + lane]), a2);
    a3 = fmaf(w3, bf2f(xtb[(size_t)q3.x * 64 + lane]), a3);
    a4 = fmaf(w4, bf2f(xtb[(size_t)q4.x * 64 + lane]), a4);
    a5 = fmaf(w5, bf2f(xtb[(size_t)q5.x * 64 + lane]), a5);
    a6 = fmaf(w6, bf2f(xtb[(size_t)q6.x * 64 + lane]), a6);
    a7 = fmaf(w7, bf2f(xtb[(size_t)q7.x * 64 + lane]), a7);
  }
  float acc = ((a0 + a1) + (a2 + a3)) + ((a4 + a5) + (a6 + a7));
  if (h == 1) part[nodeLocal][lane] = acc;
  __syncthreads();
  if (h == 1) return;
  acc += part[nodeLocal][lane];
  float xt2 = agg_act_chain(acc, lane, 64);
  float z2 = 0.f;
#pragma unroll
  for (int jj = 1; jj < 7; ++jj) {
    float wv = W2[jj * 64 + lane];
    float sjj = wsum(xt2 * wv);
    if (lane == jj) z2 = sjj;
  }
  float u2 = ub[64 + lane];
  float o = chain_with_u(z2, u2, lane, 7);
  if (lane < 8) xt3[node * 8 + lane] = o;
}

// ============== agg2 + final chain: 8 nodes/wave, masked-tail unroll-4 ========
__global__ __launch_bounds__(256) void agg2_final(const int* __restrict__ rowptr,
                                                  const uint2* __restrict__ ep,
                                                  const float* __restrict__ xt3,
                                                  float* __restrict__ out) {
  const int node = blockIdx.x * 32 + (threadIdx.x >> 3);
  const int f = threadIdx.x & 7;
  const int nc = (node < NN) ? node : (NN - 1);
  const int s0 = rowptr[nc], s1 = rowptr[nc + 1];
  float a0 = 0.f, a1 = 0.f, a2 = 0.f, a3 = 0.f;
  for (int p = s0; p < s1; p += 4) {
    int p1 = min(p + 1, s1 - 1), p2 = min(p + 2, s1 - 1), p3 = min(p + 3, s1 - 1);
    uint2 q0 = ep[p], q1 = ep[p1], q2 = ep[p2], q3 = ep[p3];
    float w0 = __uint_as_float(q0.y);
    float w1 = (p + 1 < s1) ? __uint_as_float(q1.y) : 0.f;
    float w2 = (p + 2 < s1) ? __uint_as_float(q2.y) : 0.f;
    float w3 = (p + 3 < s1) ? __uint_as_float(q3.y) : 0.f;
    a0 = fmaf(w0, xt3[(size_t)q0.x * 8 + f], a0);
    a1 = fmaf(w1, xt3[(size_t)q1.x * 8 + f], a1);
    a2 = fmaf(w2, xt3[(size_t)q2.x * 8 + f], a2);
    a3 = fmaf(w3, xt3[(size_t)q3.x * 8 + f], a3);
  }
  float acc = (a0 + a1) + (a2 + a3);
  float o = agg_act_chain8(acc, f);
  if (node < NN && f < 7) out[node * 7 + f] = o;
}

extern "C" void kernel_launch(void* const* d_in, const int* in_sizes, int n_in,
                              void* d_out, int out_size, void* d_ws, size_t ws_size,
                              hipStream_t stream) {
  const float* x = (const float*)d_in[0];
  const int* row = (const int*)d_in[1];
  const int* col = (const int*)d_in[2];
  const float* ew = (const float*)d_in[3];
  const float* W1 = (const float*)d_in[4];
  const float* b1 = (const float*)d_in[5];
  const float* W2 = (const float*)d_in[6];
  const float* b2 = (const float*)d_in[7];
  float* ws = (float*)d_ws;
  unsigned short* wfrag = (unsigned short*)(ws + WF_OFF);
  float* z1a = ws + Z1A_OFF;
  float* z1b = ws + Z1B_OFF;
  unsigned short* xtb = (unsigned short*)(ws + XTB_OFF);
  float* xt3 = ws + XT3_OFF;
  int* cnt = (int*)(ws + CNT_OFF);
  int* rowptr = (int*)(ws + ROWPTR_OFF);
  int* cur = (int*)(ws + CUR_OFF);
  int* bsum = (int*)(ws + BSUM_OFF);
  float* ub = ws + UB_OFF;
  uint2* ep = (uint2*)(ws + EP_OFF);
  float* out = (float*)d_out;

  // prep: W fragments + bias tangents + cnt zero (one launch)
  prep_wb_zero<<<dim3(289), dim3(256), 0, stream>>>(W1, b1, b2, wfrag, ub, cnt);

  // gemm (y=0,1) + histogram plane (y=2)
  gemm_hist<<<dim3(1563, 3), dim3(256), 0, stream>>>(x, wfrag, z1a, row, cnt);

  // CSR mid-chain: blocksum, then scan+apply fused
  k_blocksum<<<dim3(NB), dim3(256), 0, stream>>>(cnt, bsum);
  k_scan_apply<<<dim3(NB), dim3(256), 0, stream>>>(cnt, bsum, rowptr, cur);

  // node1 (0..12499) + scatter plane (12500..15624)
  node1_scatter<<<dim3(15625), dim3(256), 0, stream>>>(z1a, z1b, ub, xtb,
                                                       row, col, ew, cur, ep);

  // agg1: 2 waves per node (concurrent gather halves), 2 nodes/block
  agg1_node2<<<dim3(25000), dim3(256), 0, stream>>>(rowptr, ep, xtb, W2, ub, xt3);
  agg2_final<<<dim3(1563), dim3(256), 0, stream>>>(rowptr, ep, xt3, out);
}

// Round 26
// 282.766 us; speedup vs baseline: 1.0239x; 1.0239x over previous
//
#include <hip/hip_runtime.h>
#include <hip/hip_bf16.h>

#define NN 50000
#define EE 800000
#define DIN 1433
#define KTOT 1432
#define KHALF 716
#define NKT 23          // ceil(716/32) k-tiles per half
#define NB 196          // ceil(50000/256)
#define EPSC 1e-7f
#define MINN 1e-15f
#define MAXN 1e6f

typedef __attribute__((ext_vector_type(8))) short bf16x8;
typedef __attribute__((ext_vector_type(4))) float f32x4;

// ---- workspace layout (float offsets) ----
#define WF_OFF     0                          // 94208 floats
#define Z1A_OFF    94208                      // 50000*64 f32
#define Z1B_OFF    (Z1A_OFF + 3200000)        // 50000*64 f32
#define XTB_OFF    (Z1B_OFF + 3200000)        // 50000*64 bf16 = 1600000 floats
#define XT3_OFF    (XTB_OFF + 1600000)        // 50000*8 f32
#define CNT_OFF    (XT3_OFF + 400000)
#define ROWPTR_OFF (CNT_OFF + 50000)          // 50002 (padded)
#define CUR_OFF    (ROWPTR_OFF + 50002)
#define BSUM_OFF   (CUR_OFF + 50000)          // 256
#define UB_OFF     (BSUM_OFF + 256)           // 128
#define EP_OFF     (UB_OFF + 128)             // 800000 uint2

__device__ __forceinline__ float wsum(float v) {
#pragma unroll
  for (int o = 1; o < 64; o <<= 1) v += __shfl_xor(v, o, 64);
  return v;
}

__device__ __forceinline__ float gsum8(float v) {
#pragma unroll
  for (int o = 1; o < 8; o <<= 1) v += __shfl_xor(v, o, 64);
  return v;
}

__device__ __forceinline__ void split_bf(float v, unsigned int& hbits16, unsigned int& lbits16) {
  unsigned int b = __float_as_uint(v);
  unsigned int hb = b & 0xFFFF0000u;
  float r = v - __uint_as_float(hb);
  unsigned int lb = __float_as_uint(r);
  lbits16 = (lb + 0x7FFFu + ((lb >> 16) & 1u)) >> 16;
  hbits16 = hb >> 16;
}

__device__ __forceinline__ unsigned short f2bf_rne(float v) {
  unsigned int b = __float_as_uint(v);
  return (unsigned short)((b + 0x7FFFu + ((b >> 16) & 1u)) >> 16);
}
__device__ __forceinline__ float bf2f(unsigned short u) {
  return __uint_as_float(((unsigned int)u) << 16);
}

// ---- fast transcendentals (validated R8) ----
__device__ __forceinline__ float fsinh(float x) {
  float e = __expf(x);
  return 0.5f * (e - __fdividef(1.f, e));
}
__device__ __forceinline__ float facoshp(float z) {
  return __logf(z + sqrtf(fmaxf(z * z - 1.f, 0.f)));
}

// ===================== node-chain math (fast-math, validated R8) ==============
__device__ float bias_tangent(const float* b, int lane, int D) {
  const bool sp = (lane >= 1) && (lane < D);
  float bsp = sp ? b[lane] : 0.f;
  float rb = fmaxf(sqrtf(wsum(bsp * bsp)), MINN);
  float bsh = fsinh(rb);
  float hb = sp ? bsh * __fdividef(bsp, rb) : 0.f;
  float hbn2 = wsum(hb * hb);
  float hb0 = sqrtf(fmaxf(1.f + hbn2, EPSC));
  float hbyn = fmaxf(sqrtf(hbn2), MINN);
  return sp ? facoshp(fmaxf(hb0, 1.f + EPSC)) * __fdividef(hb, hbyn) : 0.f;
}

__device__ float chain_with_u(float z, float u, int lane, int D) {
  const bool sp = (lane >= 1) && (lane < D);
  float s = sp ? z : 0.f;
  float r = fmaxf(sqrtf(wsum(s * s)), MINN);
  float sh = fsinh(r);
  float y = sp ? sh * __fdividef(s, r) : 0.f;
  float yn2 = wsum(y * y);
  float x0 = sqrtf(fmaxf(1.f + yn2, EPSC));
  float y_norm = fmaxf(sqrtf(yn2), MINN);
  float ynv = sp ? __fdividef(y, y_norm) : 0.f;
  float alpha = wsum(ynv * u);
  float wsp = sp ? u - alpha * (1.f - x0) * ynv : 0.f;
  float ux = wsum(y * wsp);
  float v0 = __fdividef(ux, fmaxf(x0, EPSC));
  float vt = (lane == 0) ? v0 : wsp;
  float md = wsum(vt * vt) - 2.f * v0 * v0;
  float nu = sqrtf(fmaxf(md, EPSC));
  nu = fminf(nu, MAXN);
  float th = fmaxf(nu, MINN);
  float e = __expf(th), ei = __fdividef(1.f, e);
  float cth = 0.5f * (e + ei), sth = 0.5f * (e - ei);
  float resx = (lane == 0) ? x0 : y;
  float eres = fmaf(cth, resx, sth * __fdividef(vt, th));
  float en2 = wsum(sp ? eres * eres : 0.f);
  float e0 = sqrtf(fmaxf(1.f + en2, EPSC));
  float eyn = fmaxf(sqrtf(en2), MINN);
  return sp ? facoshp(fmaxf(e0, 1.f + EPSC)) * __fdividef(eres, eyn) : 0.f;
}

__device__ float agg_act_chain(float sin_, int lane, int D) {
  const bool sp = (lane >= 1) && (lane < D);
  float s = sp ? sin_ : 0.f;
  float r = fmaxf(sqrtf(wsum(s * s)), MINN);
  float sh = fsinh(r);
  float g = sp ? sh * __fdividef(s, r) : 0.f;
  float gn2 = wsum(g * g);
  float g0 = sqrtf(fmaxf(1.f + gn2, EPSC));
  float gyn = fmaxf(sqrtf(gn2), MINN);
  float l = sp ? facoshp(fmaxf(g0, 1.f + EPSC)) * __fdividef(g, gyn) : 0.f;
  float t = fmaxf(l, 0.f);
  float rt = fmaxf(sqrtf(wsum(t * t)), MINN);
  float sht = fsinh(rt);
  float h = sp ? sht * __fdividef(t, rt) : 0.f;
  float hn2 = wsum(h * h);
  float h0 = sqrtf(fmaxf(1.f + hn2, EPSC));
  float hyn = fmaxf(sqrtf(hn2), MINN);
  return sp ? facoshp(fmaxf(h0, 1.f + EPSC)) * __fdividef(h, hyn) : 0.f;
}

__device__ float agg_act_chain8(float sin_, int f) {
  const bool sp = (f >= 1) && (f < 7);
  float s = sp ? sin_ : 0.f;
  float r = fmaxf(sqrtf(gsum8(s * s)), MINN);
  float sh = fsinh(r);
  float g = sp ? sh * __fdividef(s, r) : 0.f;
  float gn2 = gsum8(g * g);
  float g0 = sqrtf(fmaxf(1.f + gn2, EPSC));
  float gyn = fmaxf(sqrtf(gn2), MINN);
  float l = sp ? facoshp(fmaxf(g0, 1.f + EPSC)) * __fdividef(g, gyn) : 0.f;
  float t = fmaxf(l, 0.f);
  float rt = fmaxf(sqrtf(gsum8(t * t)), MINN);
  float sht = fsinh(rt);
  float h = sp ? sht * __fdividef(t, rt) : 0.f;
  float hn2 = gsum8(h * h);
  float h0 = sqrtf(fmaxf(1.f + hn2, EPSC));
  float hyn = fmaxf(sqrtf(hn2), MINN);
  return sp ? facoshp(fmaxf(h0, 1.f + EPSC)) * __fdividef(h, hyn) : 0.f;
}

// ===== prep: W1 fragments (0..91) + bias tangents (92) + cnt zero (93..288) ===
__global__ __launch_bounds__(256) void prep_wb_zero(const float* __restrict__ W1,
                                                    const float* __restrict__ b1,
                                                    const float* __restrict__ b2,
                                                    unsigned short* __restrict__ wfrag,
                                                    float* __restrict__ ub,
                                                    int* __restrict__ cnt) {
  if (blockIdx.x >= 93) {
    int i = (blockIdx.x - 93) * 256 + threadIdx.x;
    if (i < NN) cnt[i] = 0;
    return;
  }
  if (blockIdx.x == 92) {
    const int w = threadIdx.x >> 6, lane = threadIdx.x & 63;
    if (w == 0) ub[lane] = bias_tangent(b1, lane, 64);
    else if (w == 1) ub[64 + lane] = bias_tangent(b2, lane, 7);
    return;
  }
  int idx = blockIdx.x * 256 + threadIdx.x;
  int lane = idx & 63;
  int c = (idx >> 6) & 7;
  int rest = idx >> 9;
  int kt = rest % NKT;
  int half = rest / NKT;
  int type = c >> 2, nt = c & 3;
  int col = nt * 16 + (lane & 15);
  unsigned short vals[8];
#pragma unroll
  for (int i = 0; i < 8; ++i) {
    int lk = kt * 32 + (lane >> 4) * 8 + i;
    float wv = (lk < KHALF) ? W1[col * DIN + half * KHALF + lk + 1] : 0.f;
    unsigned int h16, l16;
    split_bf(wv, h16, l16);
    vals[i] = (unsigned short)((type == 0) ? h16 : l16);
  }
  unsigned short* dst = wfrag + (((size_t)(half * NKT + kt) * 8 + c) * 64 + lane) * 8;
#pragma unroll
  for (int i = 0; i < 8; ++i) dst[i] = vals[i];
}

// ===================== CSR mid-chain ==========================================
__global__ __launch_bounds__(256) void k_blocksum(const int* __restrict__ cnt,
                                                  int* __restrict__ bsum) {
  __shared__ int wpart[4];
  int i = blockIdx.x * 256 + threadIdx.x;
  int v = (i < NN) ? cnt[i] : 0;
  int s = v;
#pragma unroll
  for (int o = 1; o < 64; o <<= 1) s += __shfl_xor(s, o, 64);
  if ((threadIdx.x & 63) == 0) wpart[threadIdx.x >> 6] = s;
  __syncthreads();
  if (threadIdx.x == 0) bsum[blockIdx.x] = wpart[0] + wpart[1] + wpart[2] + wpart[3];
}

// scanb fused into apply (parallel redundant scan; validated R23)
__global__ __launch_bounds__(256) void k_scan_apply(const int* __restrict__ cnt,
                                                    const int* __restrict__ bsum,
                                                    int* __restrict__ rowptr,
                                                    int* __restrict__ cur) {
  __shared__ int s[256];
  __shared__ int base_sh;
  const int t = threadIdx.x;
  const int b = blockIdx.x;
  int bv = (t < NB) ? bsum[t] : 0;
  s[t] = bv;
  __syncthreads();
  for (int o = 1; o < 256; o <<= 1) {
    int a = (t >= o) ? s[t - o] : 0;
    __syncthreads();
    s[t] += a;
    __syncthreads();
  }
  if (t == b) base_sh = s[b] - bv;
  __syncthreads();
  const int base = base_sh;
  __syncthreads();
  int i = b * 256 + t;
  int v = (i < NN) ? cnt[i] : 0;
  s[t] = v;
  __syncthreads();
  for (int o = 1; o < 256; o <<= 1) {
    int a = (t >= o) ? s[t - o] : 0;
    __syncthreads();
    s[t] += a;
    __syncthreads();
  }
  int ex = s[t] - v + base;
  if (i < NN) { rowptr[i] = ex; cur[i] = ex; }
  if (i == NN - 1) rowptr[NN] = EE;
}

// ======== GEMM1 half (R16 pipeline) + hist plane (blockIdx.y==2) ==============
__global__ __launch_bounds__(256) void gemm_hist(const float* __restrict__ x,
                                                 const unsigned short* __restrict__ wfrag,
                                                 float* __restrict__ z,
                                                 const int* __restrict__ row,
                                                 int* __restrict__ cnt) {
  if (blockIdx.y == 2) {   // histogram plane: 1563 blocks x 512 edges
    int e = blockIdx.x * 512 + threadIdx.x;
    if (e < EE) atomicAdd(&cnt[row[e]], 1);
    e += 256;
    if (e < EE) atomicAdd(&cnt[row[e]], 1);
    return;
  }
  __shared__ __align__(16) float XA[3 * 1024];               // 12 KB
  __shared__ __align__(16) unsigned short BB[2][8][64][8];   // 16 KB
  const int tid = threadIdx.x;
  const int w = tid >> 6, lane = tid & 63;
  const int row0 = blockIdx.x * 32;
  const int half = blockIdx.y;
  const unsigned short* wf = wfrag + (size_t)half * NKT * 4096;
  float* zp = z + (size_t)half * 3200000;
  const int nt0 = (w >> 1) * 2;

  auto stageB = [&](int kt, int p) {
    const unsigned short* src = wf + (size_t)kt * 4096 + (2 * w) * 512 + lane * 8;
    __builtin_amdgcn_global_load_lds(
        (const __attribute__((address_space(1))) unsigned int*)src,
        (__attribute__((address_space(3))) unsigned int*)(&BB[p][2 * w][0][0]), 16, 0, 0);
    __builtin_amdgcn_global_load_lds(
        (const __attribute__((address_space(1))) unsigned int*)(src + 512),
        (__attribute__((address_space(3))) unsigned int*)(&BB[p][2 * w + 1][0][0]), 16, 0, 0);
  };
  auto stageA = [&](int kt, int q) {
    const int r = w * 8 + (lane >> 3);
    const int lb = (lane & 7) ^ (r & 7);
    int grow = row0 + r; if (grow >= NN) grow = NN - 1;
    size_t off = (size_t)grow * DIN + 1 + half * KHALF + kt * 32 + lb * 4;
    if (off > (size_t)NN * DIN - 4) off = (size_t)NN * DIN - 4;   // tail clamp
    __builtin_amdgcn_global_load_lds(
        (const __attribute__((address_space(1))) unsigned int*)(x + off),
        (__attribute__((address_space(3))) unsigned int*)(XA + q * 1024 + w * 256),
        16, 0, 0);
  };

  f32x4 acc[2];
  acc[0] = (f32x4){0.f, 0.f, 0.f, 0.f};
  acc[1] = (f32x4){0.f, 0.f, 0.f, 0.f};

  stageB(0, 0);
  stageA(0, 0);
  stageA(1, 1);
  __builtin_amdgcn_sched_barrier(0);
  asm volatile("s_waitcnt vmcnt(1)" ::: "memory");
  __builtin_amdgcn_s_barrier();
  __builtin_amdgcn_sched_barrier(0);

  const int rr = (w & 1) * 16 + (lane & 15);
  const int b0 = (lane >> 4) * 2;
  const int pb0 = (b0 ^ (rr & 7)) * 4;
  const int pb1 = ((b0 + 1) ^ (rr & 7)) * 4;

  for (int kt = 0; kt < NKT; ++kt) {
    if (kt + 1 < NKT) stageB(kt + 1, (kt + 1) & 1);
    if (kt + 2 < NKT) stageA(kt + 2, (kt + 2) % 3);
    const float* xa = XA + (kt % 3) * 1024 + rr * 32;
    float4 f0 = *(const float4*)(xa + pb0);
    float4 f1 = *(const float4*)(xa + pb1);
    float af[8] = {f0.x, f0.y, f0.z, f0.w, f1.x, f1.y, f1.z, f1.w};
    unsigned int h[8], l[8];
#pragma unroll
    for (int j = 0; j < 8; ++j) split_bf(af[j], h[j], l[j]);
    bf16x8 ah, al;
#pragma unroll
    for (int j = 0; j < 8; ++j) { ah[j] = (short)h[j]; al[j] = (short)l[j]; }
    bf16x8 bh[2], bl[2];
#pragma unroll
    for (int n = 0; n < 2; ++n) {
      bh[n] = *(const bf16x8*)&BB[kt & 1][nt0 + n][lane][0];
      bl[n] = *(const bf16x8*)&BB[kt & 1][4 + nt0 + n][lane][0];
    }
    __builtin_amdgcn_s_setprio(1);
#pragma unroll
    for (int n = 0; n < 2; ++n) {
      acc[n] = __builtin_amdgcn_mfma_f32_16x16x32_bf16(ah, bh[n], acc[n], 0, 0, 0);
      acc[n] = __builtin_amdgcn_mfma_f32_16x16x32_bf16(ah, bl[n], acc[n], 0, 0, 0);
      acc[n] = __builtin_amdgcn_mfma_f32_16x16x32_bf16(al, bh[n], acc[n], 0, 0, 0);
    }
    __builtin_amdgcn_s_setprio(0);
    if (kt + 1 < NKT) {
      __builtin_amdgcn_sched_barrier(0);
      asm volatile("s_waitcnt lgkmcnt(0)" ::: "memory");
      if (kt + 2 < NKT) asm volatile("s_waitcnt vmcnt(1)" ::: "memory");
      else              asm volatile("s_waitcnt vmcnt(0)" ::: "memory");
      __builtin_amdgcn_s_barrier();
      __builtin_amdgcn_sched_barrier(0);
    }
  }
#pragma unroll
  for (int n = 0; n < 2; ++n)
#pragma unroll
    for (int i = 0; i < 4; ++i) {
      int orow = row0 + (w & 1) * 16 + (lane >> 4) * 4 + i;
      int ocol = (nt0 + n) * 16 + (lane & 15);
      if (orow < NN) zp[(size_t)orow * 64 + ocol] = acc[n][i];
    }
}

// ===== node1 (blocks 0..12499) + scatter plane (blocks 12500..15624) ==========
__global__ __launch_bounds__(256) void node1_scatter(const float* __restrict__ z1a,
                                                     const float* __restrict__ z1b,
                                                     const float* __restrict__ ub,
                                                     unsigned short* __restrict__ xtb,
                                                     const int* __restrict__ row,
                                                     const int* __restrict__ col,
                                                     const float* __restrict__ ew,
                                                     int* __restrict__ cur,
                                                     uint2* __restrict__ ep) {
  if (blockIdx.x >= 12500) {   // scatter plane: 3125 blocks
    int e = (blockIdx.x - 12500) * 256 + threadIdx.x;
    if (e < EE) {
      int p = atomicAdd(&cur[row[e]], 1);
      uint2 q;
      q.x = (unsigned int)col[e];
      q.y = __float_as_uint(ew[e]);
      ep[p] = q;
    }
    return;
  }
  const int node = blockIdx.x * 4 + (threadIdx.x >> 6);
  const int lane = threadIdx.x & 63;
  const int idx = node * 64 + lane;
  float z = z1a[idx] + z1b[idx];
  float u1 = ub[lane];
  float o = chain_with_u(z, u1, lane, 64);
  xtb[idx] = f2bf_rne(o);
}

// ===== agg1 (bf16 gather, masked-tail unroll-8) + chains + W2 =================
__global__ __launch_bounds__(256) void agg1_node2(const int* __restrict__ rowptr,
                                                  const uint2* __restrict__ ep,
                                                  const unsigned short* __restrict__ xtb,
                                                  const float* __restrict__ W2,
                                                  const float* __restrict__ ub,
                                                  float* __restrict__ xt3) {
  const int node = blockIdx.x * 4 + (threadIdx.x >> 6);
  const int lane = threadIdx.x & 63;
  const int s0 = rowptr[node], s1 = rowptr[node + 1];
  float a0 = 0.f, a1 = 0.f, a2 = 0.f, a3 = 0.f;
  float a4 = 0.f, a5 = 0.f, a6 = 0.f, a7 = 0.f;
  // masked unroll-8: last batch clamps index to s1-1 and zeroes the weight —
  // fmaf(0,finite,acc) exact; keeps 8 gathers in flight (no serial tail).
  for (int p = s0; p < s1; p += 8) {
    int p1 = min(p + 1, s1 - 1), p2 = min(p + 2, s1 - 1), p3 = min(p + 3, s1 - 1);
    int p4 = min(p + 4, s1 - 1), p5 = min(p + 5, s1 - 1), p6 = min(p + 6, s1 - 1), p7 = min(p + 7, s1 - 1);
    uint2 q0 = ep[p], q1 = ep[p1], q2 = ep[p2], q3 = ep[p3];
    uint2 q4 = ep[p4], q5 = ep[p5], q6 = ep[p6], q7 = ep[p7];
    float w0 = __uint_as_float(q0.y);
    float w1 = (p + 1 < s1) ? __uint_as_float(q1.y) : 0.f;
    float w2 = (p + 2 < s1) ? __uint_as_float(q2.y) : 0.f;
    float w3 = (p + 3 < s1) ? __uint_as_float(q3.y) : 0.f;
    float w4 = (p + 4 < s1) ? __uint_as_float(q4.y) : 0.f;
    float w5 = (p + 5 < s1) ? __uint_as_float(q5.y) : 0.f;
    float w6 = (p + 6 < s1) ? __uint_as_float(q6.y) : 0.f;
    float w7 = (p + 7 < s1) ? __uint_as_float(q7.y) : 0.f;
    a0 = fmaf(w0, bf2f(xtb[(size_t)q0.x * 64 + lane]), a0);
    a1 = fmaf(w1, bf2f(xtb[(size_t)q1.x * 64 + lane]), a1);
    a2 = fmaf(w2, bf2f(xtb[(size_t)q2.x * 64 + lane]), a2);
    a3 = fmaf(w3, bf2f(xtb[(size_t)q3.x * 64 + lane]), a3);
    a4 = fmaf(w4, bf2f(xtb[(size_t)q4.x * 64 + lane]), a4);
    a5 = fmaf(w5, bf2f(xtb[(size_t)q5.x * 64 + lane]), a5);
    a6 = fmaf(w6, bf2f(xtb[(size_t)q6.x * 64 + lane]), a6);
    a7 = fmaf(w7, bf2f(xtb[(size_t)q7.x * 64 + lane]), a7);
  }
  float acc = ((a0 + a1) + (a2 + a3)) + ((a4 + a5) + (a6 + a7));
  float xt2 = agg_act_chain(acc, lane, 64);
  float z2 = 0.f;
#pragma unroll
  for (int jj = 1; jj < 7; ++jj) {
    float wv = W2[jj * 64 + lane];
    float sjj = wsum(xt2 * wv);
    if (lane == jj) z2 = sjj;
  }
  float u2 = ub[64 + lane];
  float o = chain_with_u(z2, u2, lane, 7);
  if (lane < 8) xt3[node * 8 + lane] = o;
}

// ============== agg2 + final chain: 8 nodes/wave, masked-tail unroll-4 ========
__global__ __launch_bounds__(256) void agg2_final(const int* __restrict__ rowptr,
                                                  const uint2* __restrict__ ep,
                                                  const float* __restrict__ xt3,
                                                  float* __restrict__ out) {
  const int node = blockIdx.x * 32 + (threadIdx.x >> 3);
  const int f = threadIdx.x & 7;
  const int nc = (node < NN) ? node : (NN - 1);
  const int s0 = rowptr[nc], s1 = rowptr[nc + 1];
  float a0 = 0.f, a1 = 0.f, a2 = 0.f, a3 = 0.f;
  for (int p = s0; p < s1; p += 4) {
    int p1 = min(p + 1, s1 - 1), p2 = min(p + 2, s1 - 1), p3 = min(p + 3, s1 - 1);
    uint2 q0 = ep[p], q1 = ep[p1], q2 = ep[p2], q3 = ep[p3];
    float w0 = __uint_as_float(q0.y);
    float w1 = (p + 1 < s1) ? __uint_as_float(q1.y) : 0.f;
    float w2 = (p + 2 < s1) ? __uint_as_float(q2.y) : 0.f;
    float w3 = (p + 3 < s1) ? __uint_as_float(q3.y) : 0.f;
    a0 = fmaf(w0, xt3[(size_t)q0.x * 8 + f], a0);
    a1 = fmaf(w1, xt3[(size_t)q1.x * 8 + f], a1);
    a2 = fmaf(w2, xt3[(size_t)q2.x * 8 + f], a2);
    a3 = fmaf(w3, xt3[(size_t)q3.x * 8 + f], a3);
  }
  float acc = (a0 + a1) + (a2 + a3);
  float o = agg_act_chain8(acc, f);
  if (node < NN && f < 7) out[node * 7 + f] = o;
}

extern "C" void kernel_launch(void* const* d_in, const int* in_sizes, int n_in,
                              void* d_out, int out_size, void* d_ws, size_t ws_size,
                              hipStream_t stream) {
  const float* x = (const float*)d_in[0];
  const int* row = (const int*)d_in[1];
  const int* col = (const int*)d_in[2];
  const float* ew = (const float*)d_in[3];
  const float* W1 = (const float*)d_in[4];
  const float* b1 = (const float*)d_in[5];
  const float* W2 = (const float*)d_in[6];
  const float* b2 = (const float*)d_in[7];
  float* ws = (float*)d_ws;
  unsigned short* wfrag = (unsigned short*)(ws + WF_OFF);
  float* z1a = ws + Z1A_OFF;
  float* z1b = ws + Z1B_OFF;
  unsigned short* xtb = (unsigned short*)(ws + XTB_OFF);
  float* xt3 = ws + XT3_OFF;
  int* cnt = (int*)(ws + CNT_OFF);
  int* rowptr = (int*)(ws + ROWPTR_OFF);
  int* cur = (int*)(ws + CUR_OFF);
  int* bsum = (int*)(ws + BSUM_OFF);
  float* ub = ws + UB_OFF;
  uint2* ep = (uint2*)(ws + EP_OFF);
  float* out = (float*)d_out;

  // prep: W fragments + bias tangents + cnt zero (one launch)
  prep_wb_zero<<<dim3(289), dim3(256), 0, stream>>>(W1, b1, b2, wfrag, ub, cnt);

  // gemm (y=0,1) + histogram plane (y=2)
  gemm_hist<<<dim3(1563, 3), dim3(256), 0, stream>>>(x, wfrag, z1a, row, cnt);

  // CSR mid-chain: blocksum, then scan+apply fused
  k_blocksum<<<dim3(NB), dim3(256), 0, stream>>>(cnt, bsum);
  k_scan_apply<<<dim3(NB), dim3(256), 0, stream>>>(cnt, bsum, rowptr, cur);

  // node1 (0..12499) + scatter plane (12500..15624)
  node1_scatter<<<dim3(15625), dim3(256), 0, stream>>>(z1a, z1b, ub, xtb,
                                                       row, col, ew, cur, ep);

  agg1_node2<<<dim3(12500), dim3(256), 0, stream>>>(rowptr, ep, xtb, W2, ub, xt3);
  agg2_final<<<dim3(1563), dim3(256), 0, stream>>>(rowptr, ep, xt3, out);
}

// Round 27
// 268.737 us; speedup vs baseline: 1.0774x; 1.0522x over previous
//
#include <hip/hip_runtime.h>
#include <hip/hip_bf16.h>

#define NN 50000
#define EE 800000
#define DIN 1433
#define KTOT 1432
#define KHALF 716
#define NKT 23          // ceil(716/32) k-tiles per half
#define NB 196          // ceil(50000/256)
#define EPSC 1e-7f
#define MINN 1e-15f
#define MAXN 1e6f

typedef __attribute__((ext_vector_type(8))) short bf16x8;
typedef __attribute__((ext_vector_type(4))) float f32x4;

// ---- workspace layout (float offsets) ----
#define WF_OFF     0                          // 94208 floats
#define Z1A_OFF    94208                      // 50000*64 f32
#define Z1B_OFF    (Z1A_OFF + 3200000)        // 50000*64 f32
#define XTB_OFF    (Z1B_OFF + 3200000)        // 50000*64 bf16 = 1600000 floats
#define XT3_OFF    (XTB_OFF + 1600000)        // 50000*8 f32
#define CNT_OFF    (XT3_OFF + 400000)
#define ROWPTR_OFF (CNT_OFF + 50000)          // 50002 (padded)
#define CUR_OFF    (ROWPTR_OFF + 50002)
#define BSUM_OFF   (CUR_OFF + 50000)          // 256
#define UB_OFF     (BSUM_OFF + 256)           // 128
#define EP_OFF     (UB_OFF + 128)             // 800000 uint2

__device__ __forceinline__ float wsum(float v) {
#pragma unroll
  for (int o = 1; o < 64; o <<= 1) v += __shfl_xor(v, o, 64);
  return v;
}

__device__ __forceinline__ float gsum8(float v) {
#pragma unroll
  for (int o = 1; o < 8; o <<= 1) v += __shfl_xor(v, o, 64);
  return v;
}

__device__ __forceinline__ void split_bf(float v, unsigned int& hbits16, unsigned int& lbits16) {
  unsigned int b = __float_as_uint(v);
  unsigned int hb = b & 0xFFFF0000u;
  float r = v - __uint_as_float(hb);
  unsigned int lb = __float_as_uint(r);
  lbits16 = (lb + 0x7FFFu + ((lb >> 16) & 1u)) >> 16;
  hbits16 = hb >> 16;
}

__device__ __forceinline__ unsigned short f2bf_rne(float v) {
  unsigned int b = __float_as_uint(v);
  return (unsigned short)((b + 0x7FFFu + ((b >> 16) & 1u)) >> 16);
}
__device__ __forceinline__ float bf2f(unsigned short u) {
  return __uint_as_float(((unsigned int)u) << 16);
}

// ---- fast transcendentals (validated R8) ----
__device__ __forceinline__ float fsinh(float x) {
  float e = __expf(x);
  return 0.5f * (e - __fdividef(1.f, e));
}
__device__ __forceinline__ float facoshp(float z) {
  return __logf(z + sqrtf(fmaxf(z * z - 1.f, 0.f)));
}

// ===================== node-chain math (fast-math, validated R8) ==============
__device__ float bias_tangent(const float* b, int lane, int D) {
  const bool sp = (lane >= 1) && (lane < D);
  float bsp = sp ? b[lane] : 0.f;
  float rb = fmaxf(sqrtf(wsum(bsp * bsp)), MINN);
  float bsh = fsinh(rb);
  float hb = sp ? bsh * __fdividef(bsp, rb) : 0.f;
  float hbn2 = wsum(hb * hb);
  float hb0 = sqrtf(fmaxf(1.f + hbn2, EPSC));
  float hbyn = fmaxf(sqrtf(hbn2), MINN);
  return sp ? facoshp(fmaxf(hb0, 1.f + EPSC)) * __fdividef(hb, hbyn) : 0.f;
}

__device__ float chain_with_u(float z, float u, int lane, int D) {
  const bool sp = (lane >= 1) && (lane < D);
  float s = sp ? z : 0.f;
  float r = fmaxf(sqrtf(wsum(s * s)), MINN);
  float sh = fsinh(r);
  float y = sp ? sh * __fdividef(s, r) : 0.f;
  float yn2 = wsum(y * y);
  float x0 = sqrtf(fmaxf(1.f + yn2, EPSC));
  float y_norm = fmaxf(sqrtf(yn2), MINN);
  float ynv = sp ? __fdividef(y, y_norm) : 0.f;
  float alpha = wsum(ynv * u);
  float wsp = sp ? u - alpha * (1.f - x0) * ynv : 0.f;
  float ux = wsum(y * wsp);
  float v0 = __fdividef(ux, fmaxf(x0, EPSC));
  float vt = (lane == 0) ? v0 : wsp;
  float md = wsum(vt * vt) - 2.f * v0 * v0;
  float nu = sqrtf(fmaxf(md, EPSC));
  nu = fminf(nu, MAXN);
  float th = fmaxf(nu, MINN);
  float e = __expf(th), ei = __fdividef(1.f, e);
  float cth = 0.5f * (e + ei), sth = 0.5f * (e - ei);
  float resx = (lane == 0) ? x0 : y;
  float eres = fmaf(cth, resx, sth * __fdividef(vt, th));
  float en2 = wsum(sp ? eres * eres : 0.f);
  float e0 = sqrtf(fmaxf(1.f + en2, EPSC));
  float eyn = fmaxf(sqrtf(en2), MINN);
  return sp ? facoshp(fmaxf(e0, 1.f + EPSC)) * __fdividef(eres, eyn) : 0.f;
}

__device__ float agg_act_chain(float sin_, int lane, int D) {
  const bool sp = (lane >= 1) && (lane < D);
  float s = sp ? sin_ : 0.f;
  float r = fmaxf(sqrtf(wsum(s * s)), MINN);
  float sh = fsinh(r);
  float g = sp ? sh * __fdividef(s, r) : 0.f;
  float gn2 = wsum(g * g);
  float g0 = sqrtf(fmaxf(1.f + gn2, EPSC));
  float gyn = fmaxf(sqrtf(gn2), MINN);
  float l = sp ? facoshp(fmaxf(g0, 1.f + EPSC)) * __fdividef(g, gyn) : 0.f;
  float t = fmaxf(l, 0.f);
  float rt = fmaxf(sqrtf(wsum(t * t)), MINN);
  float sht = fsinh(rt);
  float h = sp ? sht * __fdividef(t, rt) : 0.f;
  float hn2 = wsum(h * h);
  float h0 = sqrtf(fmaxf(1.f + hn2, EPSC));
  float hyn = fmaxf(sqrtf(hn2), MINN);
  return sp ? facoshp(fmaxf(h0, 1.f + EPSC)) * __fdividef(h, hyn) : 0.f;
}

__device__ float agg_act_chain8(float sin_, int f) {
  const bool sp = (f >= 1) && (f < 7);
  float s = sp ? sin_ : 0.f;
  float r = fmaxf(sqrtf(gsum8(s * s)), MINN);
  float sh = fsinh(r);
  float g = sp ? sh * __fdividef(s, r) : 0.f;
  float gn2 = gsum8(g * g);
  float g0 = sqrtf(fmaxf(1.f + gn2, EPSC));
  float gyn = fmaxf(sqrtf(gn2), MINN);
  float l = sp ? facoshp(fmaxf(g0, 1.f + EPSC)) * __fdividef(g, gyn) : 0.f;
  float t = fmaxf(l, 0.f);
  float rt = fmaxf(sqrtf(gsum8(t * t)), MINN);
  float sht = fsinh(rt);
  float h = sp ? sht * __fdividef(t, rt) : 0.f;
  float hn2 = gsum8(h * h);
  float h0 = sqrtf(fmaxf(1.f + hn2, EPSC));
  float hyn = fmaxf(sqrtf(hn2), MINN);
  return sp ? facoshp(fmaxf(h0, 1.f + EPSC)) * __fdividef(h, hyn) : 0.f;
}

// ===== prep: W1 fragments (0..91) + bias tangents (92) + cnt zero (93..288) ===
__global__ __launch_bounds__(256) void prep_wb_zero(const float* __restrict__ W1,
                                                    const float* __restrict__ b1,
                                                    const float* __restrict__ b2,
                                                    unsigned short* __restrict__ wfrag,
                                                    float* __restrict__ ub,
                                                    int* __restrict__ cnt) {
  if (blockIdx.x >= 93) {
    int i = (blockIdx.x - 93) * 256 + threadIdx.x;
    if (i < NN) cnt[i] = 0;
    return;
  }
  if (blockIdx.x == 92) {
    const int w = threadIdx.x >> 6, lane = threadIdx.x & 63;
    if (w == 0) ub[lane] = bias_tangent(b1, lane, 64);
    else if (w == 1) ub[64 + lane] = bias_tangent(b2, lane, 7);
    return;
  }
  int idx = blockIdx.x * 256 + threadIdx.x;
  int lane = idx & 63;
  int c = (idx >> 6) & 7;
  int rest = idx >> 9;
  int kt = rest % NKT;
  int half = rest / NKT;
  int type = c >> 2, nt = c & 3;
  int col = nt * 16 + (lane & 15);
  unsigned short vals[8];
#pragma unroll
  for (int i = 0; i < 8; ++i) {
    int lk = kt * 32 + (lane >> 4) * 8 + i;
    float wv = (lk < KHALF) ? W1[col * DIN + half * KHALF + lk + 1] : 0.f;
    unsigned int h16, l16;
    split_bf(wv, h16, l16);
    vals[i] = (unsigned short)((type == 0) ? h16 : l16);
  }
  unsigned short* dst = wfrag + (((size_t)(half * NKT + kt) * 8 + c) * 64 + lane) * 8;
#pragma unroll
  for (int i = 0; i < 8; ++i) dst[i] = vals[i];
}

// ===================== CSR mid-chain ==========================================
__global__ __launch_bounds__(256) void k_blocksum(const int* __restrict__ cnt,
                                                  int* __restrict__ bsum) {
  __shared__ int wpart[4];
  int i = blockIdx.x * 256 + threadIdx.x;
  int v = (i < NN) ? cnt[i] : 0;
  int s = v;
#pragma unroll
  for (int o = 1; o < 64; o <<= 1) s += __shfl_xor(s, o, 64);
  if ((threadIdx.x & 63) == 0) wpart[threadIdx.x >> 6] = s;
  __syncthreads();
  if (threadIdx.x == 0) bsum[blockIdx.x] = wpart[0] + wpart[1] + wpart[2] + wpart[3];
}

// scanb fused into apply (parallel redundant scan; validated R23)
__global__ __launch_bounds__(256) void k_scan_apply(const int* __restrict__ cnt,
                                                    const int* __restrict__ bsum,
                                                    int* __restrict__ rowptr,
                                                    int* __restrict__ cur) {
  __shared__ int s[256];
  __shared__ int base_sh;
  const int t = threadIdx.x;
  const int b = blockIdx.x;
  int bv = (t < NB) ? bsum[t] : 0;
  s[t] = bv;
  __syncthreads();
  for (int o = 1; o < 256; o <<= 1) {
    int a = (t >= o) ? s[t - o] : 0;
    __syncthreads();
    s[t] += a;
    __syncthreads();
  }
  if (t == b) base_sh = s[b] - bv;
  __syncthreads();
  const int base = base_sh;
  __syncthreads();
  int i = b * 256 + t;
  int v = (i < NN) ? cnt[i] : 0;
  s[t] = v;
  __syncthreads();
  for (int o = 1; o < 256; o <<= 1) {
    int a = (t >= o) ? s[t - o] : 0;
    __syncthreads();
    s[t] += a;
    __syncthreads();
  }
  int ex = s[t] - v + base;
  if (i < NN) { rowptr[i] = ex; cur[i] = ex; }
  if (i == NN - 1) rowptr[NN] = EE;
}

// ======== GEMM1 half: BM=64 + counted pipeline + hist plane (blockIdx.y==2) ===
// First combination of BM=64 with the R13+ counted-vmcnt pipeline: halves
// block count & B L2 traffic, doubles per-wave MFMA density (12/iter).
// LDS 40KB -> 4 blocks/CU. Per-iter VMEM/wave: B(kt+1)x2 then A(kt+2)x2;
// wait vmcnt(2) leaves only A(kt+2) in flight.
__global__ __launch_bounds__(256) void gemm_hist(const float* __restrict__ x,
                                                 const unsigned short* __restrict__ wfrag,
                                                 float* __restrict__ z,
                                                 const int* __restrict__ row,
                                                 int* __restrict__ cnt) {
  if (blockIdx.y == 2) {   // histogram plane: 782 blocks x 1024 edges
    int e = blockIdx.x * 1024 + threadIdx.x;
#pragma unroll
    for (int i = 0; i < 4; ++i) {
      if (e < EE) atomicAdd(&cnt[row[e]], 1);
      e += 256;
    }
    return;
  }
  __shared__ __align__(16) float XA[3 * 2048];               // 24 KB: 3x [64][32] f32
  __shared__ __align__(16) unsigned short BB[2][8][64][8];   // 16 KB
  const int tid = threadIdx.x;
  const int w = tid >> 6, lane = tid & 63;
  const int row0 = blockIdx.x * 64;
  const int half = blockIdx.y;
  const unsigned short* wf = wfrag + (size_t)half * NKT * 4096;
  float* zp = z + (size_t)half * 3200000;
  const int nt0 = (w >> 1) * 2;

  auto stageB = [&](int kt, int p) {
    const unsigned short* src = wf + (size_t)kt * 4096 + (2 * w) * 512 + lane * 8;
    __builtin_amdgcn_global_load_lds(
        (const __attribute__((address_space(1))) unsigned int*)src,
        (__attribute__((address_space(3))) unsigned int*)(&BB[p][2 * w][0][0]), 16, 0, 0);
    __builtin_amdgcn_global_load_lds(
        (const __attribute__((address_space(1))) unsigned int*)(src + 512),
        (__attribute__((address_space(3))) unsigned int*)(&BB[p][2 * w + 1][0][0]), 16, 0, 0);
  };
  // A tile [64][32] f32: wave w stages rows w*16..w*16+15 with 2x 16B gl_lds.
  auto stageA = [&](int kt, int q) {
#pragma unroll
    for (int i = 0; i < 2; ++i) {
      const int r = w * 16 + i * 8 + (lane >> 3);
      const int lb = (lane & 7) ^ (r & 7);          // source block pre-swizzle
      int grow = row0 + r; if (grow >= NN) grow = NN - 1;
      size_t off = (size_t)grow * DIN + 1 + half * KHALF + kt * 32 + lb * 4;
      if (off > (size_t)NN * DIN - 4) off = (size_t)NN * DIN - 4;   // tail clamp
      __builtin_amdgcn_global_load_lds(
          (const __attribute__((address_space(1))) unsigned int*)(x + off),
          (__attribute__((address_space(3))) unsigned int*)(XA + q * 2048 + w * 512 + i * 256),
          16, 0, 0);
    }
  };

  f32x4 acc[2][2];
#pragma unroll
  for (int m = 0; m < 2; ++m)
#pragma unroll
    for (int n = 0; n < 2; ++n) acc[m][n] = (f32x4){0.f, 0.f, 0.f, 0.f};

  stageB(0, 0);
  stageA(0, 0);
  stageA(1, 1);
  __builtin_amdgcn_sched_barrier(0);
  asm volatile("s_waitcnt vmcnt(2)" ::: "memory");
  __builtin_amdgcn_s_barrier();
  __builtin_amdgcn_sched_barrier(0);

  const int rrb = (w & 1) * 32 + (lane & 15);   // row frag m: rrb + m*16
  const int b0 = (lane >> 4) * 2;

  for (int kt = 0; kt < NKT; ++kt) {
    if (kt + 1 < NKT) stageB(kt + 1, (kt + 1) & 1);
    if (kt + 2 < NKT) stageA(kt + 2, (kt + 2) % 3);
    const float* xaq = XA + (kt % 3) * 2048;
    bf16x8 ah[2], al[2];
#pragma unroll
    for (int m = 0; m < 2; ++m) {
      const int rr = rrb + m * 16;
      const float* xa = xaq + rr * 32;
      float4 f0 = *(const float4*)(xa + ((b0 ^ (rr & 7)) * 4));
      float4 f1 = *(const float4*)(xa + (((b0 + 1) ^ (rr & 7)) * 4));
      float af[8] = {f0.x, f0.y, f0.z, f0.w, f1.x, f1.y, f1.z, f1.w};
      unsigned int h[8], l[8];
#pragma unroll
      for (int j = 0; j < 8; ++j) split_bf(af[j], h[j], l[j]);
#pragma unroll
      for (int j = 0; j < 8; ++j) { ah[m][j] = (short)h[j]; al[m][j] = (short)l[j]; }
    }
    bf16x8 bh[2], bl[2];
#pragma unroll
    for (int n = 0; n < 2; ++n) {
      bh[n] = *(const bf16x8*)&BB[kt & 1][nt0 + n][lane][0];
      bl[n] = *(const bf16x8*)&BB[kt & 1][4 + nt0 + n][lane][0];
    }
    __builtin_amdgcn_s_setprio(1);
#pragma unroll
    for (int m = 0; m < 2; ++m)
#pragma unroll
      for (int n = 0; n < 2; ++n) {
        acc[m][n] = __builtin_amdgcn_mfma_f32_16x16x32_bf16(ah[m], bh[n], acc[m][n], 0, 0, 0);
        acc[m][n] = __builtin_amdgcn_mfma_f32_16x16x32_bf16(ah[m], bl[n], acc[m][n], 0, 0, 0);
        acc[m][n] = __builtin_amdgcn_mfma_f32_16x16x32_bf16(al[m], bh[n], acc[m][n], 0, 0, 0);
      }
    __builtin_amdgcn_s_setprio(0);
    if (kt + 1 < NKT) {
      __builtin_amdgcn_sched_barrier(0);
      asm volatile("s_waitcnt lgkmcnt(0)" ::: "memory");
      if (kt + 2 < NKT) asm volatile("s_waitcnt vmcnt(2)" ::: "memory");
      else              asm volatile("s_waitcnt vmcnt(0)" ::: "memory");
      __builtin_amdgcn_s_barrier();
      __builtin_amdgcn_sched_barrier(0);
    }
  }
  // epilogue: D row=(lane>>4)*4+i, col=lane&15
#pragma unroll
  for (int m = 0; m < 2; ++m)
#pragma unroll
    for (int n = 0; n < 2; ++n)
#pragma unroll
      for (int i = 0; i < 4; ++i) {
        int orow = row0 + (w & 1) * 32 + m * 16 + (lane >> 4) * 4 + i;
        int ocol = (nt0 + n) * 16 + (lane & 15);
        if (orow < NN) zp[(size_t)orow * 64 + ocol] = acc[m][n][i];
      }
}

// ===== node1 (blocks 0..12499) + scatter plane (blocks 12500..15624) ==========
__global__ __launch_bounds__(256) void node1_scatter(const float* __restrict__ z1a,
                                                     const float* __restrict__ z1b,
                                                     const float* __restrict__ ub,
                                                     unsigned short* __restrict__ xtb,
                                                     const int* __restrict__ row,
                                                     const int* __restrict__ col,
                                                     const float* __restrict__ ew,
                                                     int* __restrict__ cur,
                                                     uint2* __restrict__ ep) {
  if (blockIdx.x >= 12500) {   // scatter plane: 3125 blocks
    int e = (blockIdx.x - 12500) * 256 + threadIdx.x;
    if (e < EE) {
      int p = atomicAdd(&cur[row[e]], 1);
      uint2 q;
      q.x = (unsigned int)col[e];
      q.y = __float_as_uint(ew[e]);
      ep[p] = q;
    }
    return;
  }
  const int node = blockIdx.x * 4 + (threadIdx.x >> 6);
  const int lane = threadIdx.x & 63;
  const int idx = node * 64 + lane;
  float z = z1a[idx] + z1b[idx];
  float u1 = ub[lane];
  float o = chain_with_u(z, u1, lane, 64);
  xtb[idx] = f2bf_rne(o);
}

// ===== agg1 (bf16 gather, masked-tail unroll-8) + chains + W2 =================
__global__ __launch_bounds__(256) void agg1_node2(const int* __restrict__ rowptr,
                                                  const uint2* __restrict__ ep,
                                                  const unsigned short* __restrict__ xtb,
                                                  const float* __restrict__ W2,
                                                  const float* __restrict__ ub,
                                                  float* __restrict__ xt3) {
  const int node = blockIdx.x * 4 + (threadIdx.x >> 6);
  const int lane = threadIdx.x & 63;
  const int s0 = rowptr[node], s1 = rowptr[node + 1];
  float a0 = 0.f, a1 = 0.f, a2 = 0.f, a3 = 0.f;
  float a4 = 0.f, a5 = 0.f, a6 = 0.f, a7 = 0.f;
  for (int p = s0; p < s1; p += 8) {
    int p1 = min(p + 1, s1 - 1), p2 = min(p + 2, s1 - 1), p3 = min(p + 3, s1 - 1);
    int p4 = min(p + 4, s1 - 1), p5 = min(p + 5, s1 - 1), p6 = min(p + 6, s1 - 1), p7 = min(p + 7, s1 - 1);
    uint2 q0 = ep[p], q1 = ep[p1], q2 = ep[p2], q3 = ep[p3];
    uint2 q4 = ep[p4], q5 = ep[p5], q6 = ep[p6], q7 = ep[p7];
    float w0 = __uint_as_float(q0.y);
    float w1 = (p + 1 < s1) ? __uint_as_float(q1.y) : 0.f;
    float w2 = (p + 2 < s1) ? __uint_as_float(q2.y) : 0.f;
    float w3 = (p + 3 < s1) ? __uint_as_float(q3.y) : 0.f;
    float w4 = (p + 4 < s1) ? __uint_as_float(q4.y) : 0.f;
    float w5 = (p + 5 < s1) ? __uint_as_float(q5.y) : 0.f;
    float w6 = (p + 6 < s1) ? __uint_as_float(q6.y) : 0.f;
    float w7 = (p + 7 < s1) ? __uint_as_float(q7.y) : 0.f;
    a0 = fmaf(w0, bf2f(xtb[(size_t)q0.x * 64 + lane]), a0);
    a1 = fmaf(w1, bf2f(xtb[(size_t)q1.x * 64 + lane]), a1);
    a2 = fmaf(w2, bf2f(xtb[(size_t)q2.x * 64 + lane]), a2);
    a3 = fmaf(w3, bf2f(xtb[(size_t)q3.x * 64 + lane]), a3);
    a4 = fmaf(w4, bf2f(xtb[(size_t)q4.x * 64 + lane]), a4);
    a5 = fmaf(w5, bf2f(xtb[(size_t)q5.x * 64 + lane]), a5);
    a6 = fmaf(w6, bf2f(xtb[(size_t)q6.x * 64 + lane]), a6);
    a7 = fmaf(w7, bf2f(xtb[(size_t)q7.x * 64 + lane]), a7);
  }
  float acc = ((a0 + a1) + (a2 + a3)) + ((a4 + a5) + (a6 + a7));
  float xt2 = agg_act_chain(acc, lane, 64);
  float z2 = 0.f;
#pragma unroll
  for (int jj = 1; jj < 7; ++jj) {
    float wv = W2[jj * 64 + lane];
    float sjj = wsum(xt2 * wv);
    if (lane == jj) z2 = sjj;
  }
  float u2 = ub[64 + lane];
  float o = chain_with_u(z2, u2, lane, 7);
  if (lane < 8) xt3[node * 8 + lane] = o;
}

// ============== agg2 + final chain: 8 nodes/wave, masked-tail unroll-4 ========
__global__ __launch_bounds__(256) void agg2_final(const int* __restrict__ rowptr,
                                                  const uint2* __restrict__ ep,
                                                  const float* __restrict__ xt3,
                                                  float* __restrict__ out) {
  const int node = blockIdx.x * 32 + (threadIdx.x >> 3);
  const int f = threadIdx.x & 7;
  const int nc = (node < NN) ? node : (NN - 1);
  const int s0 = rowptr[nc], s1 = rowptr[nc + 1];
  float a0 = 0.f, a1 = 0.f, a2 = 0.f, a3 = 0.f;
  for (int p = s0; p < s1; p += 4) {
    int p1 = min(p + 1, s1 - 1), p2 = min(p + 2, s1 - 1), p3 = min(p + 3, s1 - 1);
    uint2 q0 = ep[p], q1 = ep[p1], q2 = ep[p2], q3 = ep[p3];
    float w0 = __uint_as_float(q0.y);
    float w1 = (p + 1 < s1) ? __uint_as_float(q1.y) : 0.f;
    float w2 = (p + 2 < s1) ? __uint_as_float(q2.y) : 0.f;
    float w3 = (p + 3 < s1) ? __uint_as_float(q3.y) : 0.f;
    a0 = fmaf(w0, xt3[(size_t)q0.x * 8 + f], a0);
    a1 = fmaf(w1, xt3[(size_t)q1.x * 8 + f], a1);
    a2 = fmaf(w2, xt3[(size_t)q2.x * 8 + f], a2);
    a3 = fmaf(w3, xt3[(size_t)q3.x * 8 + f], a3);
  }
  float acc = (a0 + a1) + (a2 + a3);
  float o = agg_act_chain8(acc, f);
  if (node < NN && f < 7) out[node * 7 + f] = o;
}

extern "C" void kernel_launch(void* const* d_in, const int* in_sizes, int n_in,
                              void* d_out, int out_size, void* d_ws, size_t ws_size,
                              hipStream_t stream) {
  const float* x = (const float*)d_in[0];
  const int* row = (const int*)d_in[1];
  const int* col = (const int*)d_in[2];
  const float* ew = (const float*)d_in[3];
  const float* W1 = (const float*)d_in[4];
  const float* b1 = (const float*)d_in[5];
  const float* W2 = (const float*)d_in[6];
  const float* b2 = (const float*)d_in[7];
  float* ws = (float*)d_ws;
  unsigned short* wfrag = (unsigned short*)(ws + WF_OFF);
  float* z1a = ws + Z1A_OFF;
  float* z1b = ws + Z1B_OFF;
  unsigned short* xtb = (unsigned short*)(ws + XTB_OFF);
  float* xt3 = ws + XT3_OFF;
  int* cnt = (int*)(ws + CNT_OFF);
  int* rowptr = (int*)(ws + ROWPTR_OFF);
  int* cur = (int*)(ws + CUR_OFF);
  int* bsum = (int*)(ws + BSUM_OFF);
  float* ub = ws + UB_OFF;
  uint2* ep = (uint2*)(ws + EP_OFF);
  float* out = (float*)d_out;

  // prep: W fragments + bias tangents + cnt zero (one launch)
  prep_wb_zero<<<dim3(289), dim3(256), 0, stream>>>(W1, b1, b2, wfrag, ub, cnt);

  // gemm BM=64 (y=0,1) + histogram plane (y=2)
  gemm_hist<<<dim3(782, 3), dim3(256), 0, stream>>>(x, wfrag, z1a, row, cnt);

  // CSR mid-chain: blocksum, then scan+apply fused
  k_blocksum<<<dim3(NB), dim3(256), 0, stream>>>(cnt, bsum);
  k_scan_apply<<<dim3(NB), dim3(256), 0, stream>>>(cnt, bsum, rowptr, cur);

  // node1 (0..12499) + scatter plane (12500..15624)
  node1_scatter<<<dim3(15625), dim3(256), 0, stream>>>(z1a, z1b, ub, xtb,
                                                       row, col, ew, cur, ep);

  agg1_node2<<<dim3(12500), dim3(256), 0, stream>>>(rowptr, ep, xtb, W2, ub, xt3);
  agg2_final<<<dim3(1563), dim3(256), 0, stream>>>(rowptr, ep, xt3, out);
}

// Round 28
// 268.332 us; speedup vs baseline: 1.0790x; 1.0015x over previous
//
#include <hip/hip_runtime.h>
#include <hip/hip_bf16.h>

#define NN 50000
#define EE 800000
#define DIN 1433
#define KTOT 1432
#define KHALF 716
#define NKT 23          // ceil(716/32) k-tiles per half
#define NB 196          // ceil(50000/256)
#define EPSC 1e-7f
#define MINN 1e-15f
#define MAXN 1e6f

typedef __attribute__((ext_vector_type(8))) short bf16x8;
typedef __attribute__((ext_vector_type(4))) float f32x4;

// ---- workspace layout (float offsets) ----
#define WF_OFF     0                          // 94208 floats
#define Z1A_OFF    94208                      // 50000*64 f32
#define Z1B_OFF    (Z1A_OFF + 3200000)        // 50000*64 f32
#define XTB_OFF    (Z1B_OFF + 3200000)        // 50000*64 bf16 = 1600000 floats
#define XT3_OFF    (XTB_OFF + 1600000)        // 50000*8 f32
#define CNT_OFF    (XT3_OFF + 400000)
#define ROWPTR_OFF (CNT_OFF + 50000)          // 50002 (padded)
#define CUR_OFF    (ROWPTR_OFF + 50002)
#define BSUM_OFF   (CUR_OFF + 50000)          // 256
#define UB_OFF     (BSUM_OFF + 256)           // 128
#define EP_OFF     (UB_OFF + 128)             // 800000 uint2

__device__ __forceinline__ float wsum(float v) {
#pragma unroll
  for (int o = 1; o < 64; o <<= 1) v += __shfl_xor(v, o, 64);
  return v;
}

__device__ __forceinline__ float gsum8(float v) {
#pragma unroll
  for (int o = 1; o < 8; o <<= 1) v += __shfl_xor(v, o, 64);
  return v;
}

__device__ __forceinline__ void split_bf(float v, unsigned int& hbits16, unsigned int& lbits16) {
  unsigned int b = __float_as_uint(v);
  unsigned int hb = b & 0xFFFF0000u;
  float r = v - __uint_as_float(hb);
  unsigned int lb = __float_as_uint(r);
  lbits16 = (lb + 0x7FFFu + ((lb >> 16) & 1u)) >> 16;
  hbits16 = hb >> 16;
}

__device__ __forceinline__ unsigned short f2bf_rne(float v) {
  unsigned int b = __float_as_uint(v);
  return (unsigned short)((b + 0x7FFFu + ((b >> 16) & 1u)) >> 16);
}
__device__ __forceinline__ float bf2f(unsigned short u) {
  return __uint_as_float(((unsigned int)u) << 16);
}

// ---- fast transcendentals (validated R8) ----
__device__ __forceinline__ float fsinh(float x) {
  float e = __expf(x);
  return 0.5f * (e - __fdividef(1.f, e));
}
__device__ __forceinline__ float facoshp(float z) {
  return __logf(z + sqrtf(fmaxf(z * z - 1.f, 0.f)));
}

// ===================== node-chain math (fast-math, validated R8) ==============
__device__ float bias_tangent(const float* b, int lane, int D) {
  const bool sp = (lane >= 1) && (lane < D);
  float bsp = sp ? b[lane] : 0.f;
  float rb = fmaxf(sqrtf(wsum(bsp * bsp)), MINN);
  float bsh = fsinh(rb);
  float hb = sp ? bsh * __fdividef(bsp, rb) : 0.f;
  float hbn2 = wsum(hb * hb);
  float hb0 = sqrtf(fmaxf(1.f + hbn2, EPSC));
  float hbyn = fmaxf(sqrtf(hbn2), MINN);
  return sp ? facoshp(fmaxf(hb0, 1.f + EPSC)) * __fdividef(hb, hbyn) : 0.f;
}

__device__ float chain_with_u(float z, float u, int lane, int D) {
  const bool sp = (lane >= 1) && (lane < D);
  float s = sp ? z : 0.f;
  float r = fmaxf(sqrtf(wsum(s * s)), MINN);
  float sh = fsinh(r);
  float y = sp ? sh * __fdividef(s, r) : 0.f;
  float yn2 = wsum(y * y);
  float x0 = sqrtf(fmaxf(1.f + yn2, EPSC));
  float y_norm = fmaxf(sqrtf(yn2), MINN);
  float ynv = sp ? __fdividef(y, y_norm) : 0.f;
  float alpha = wsum(ynv * u);
  float wsp = sp ? u - alpha * (1.f - x0) * ynv : 0.f;
  float ux = wsum(y * wsp);
  float v0 = __fdividef(ux, fmaxf(x0, EPSC));
  float vt = (lane == 0) ? v0 : wsp;
  float md = wsum(vt * vt) - 2.f * v0 * v0;
  float nu = sqrtf(fmaxf(md, EPSC));
  nu = fminf(nu, MAXN);
  float th = fmaxf(nu, MINN);
  float e = __expf(th), ei = __fdividef(1.f, e);
  float cth = 0.5f * (e + ei), sth = 0.5f * (e - ei);
  float resx = (lane == 0) ? x0 : y;
  float eres = fmaf(cth, resx, sth * __fdividef(vt, th));
  float en2 = wsum(sp ? eres * eres : 0.f);
  float e0 = sqrtf(fmaxf(1.f + en2, EPSC));
  float eyn = fmaxf(sqrtf(en2), MINN);
  return sp ? facoshp(fmaxf(e0, 1.f + EPSC)) * __fdividef(eres, eyn) : 0.f;
}

__device__ float agg_act_chain(float sin_, int lane, int D) {
  const bool sp = (lane >= 1) && (lane < D);
  float s = sp ? sin_ : 0.f;
  float r = fmaxf(sqrtf(wsum(s * s)), MINN);
  float sh = fsinh(r);
  float g = sp ? sh * __fdividef(s, r) : 0.f;
  float gn2 = wsum(g * g);
  float g0 = sqrtf(fmaxf(1.f + gn2, EPSC));
  float gyn = fmaxf(sqrtf(gn2), MINN);
  float l = sp ? facoshp(fmaxf(g0, 1.f + EPSC)) * __fdividef(g, gyn) : 0.f;
  float t = fmaxf(l, 0.f);
  float rt = fmaxf(sqrtf(wsum(t * t)), MINN);
  float sht = fsinh(rt);
  float h = sp ? sht * __fdividef(t, rt) : 0.f;
  float hn2 = wsum(h * h);
  float h0 = sqrtf(fmaxf(1.f + hn2, EPSC));
  float hyn = fmaxf(sqrtf(hn2), MINN);
  return sp ? facoshp(fmaxf(h0, 1.f + EPSC)) * __fdividef(h, hyn) : 0.f;
}

__device__ float agg_act_chain8(float sin_, int f) {
  const bool sp = (f >= 1) && (f < 7);
  float s = sp ? sin_ : 0.f;
  float r = fmaxf(sqrtf(gsum8(s * s)), MINN);
  float sh = fsinh(r);
  float g = sp ? sh * __fdividef(s, r) : 0.f;
  float gn2 = gsum8(g * g);
  float g0 = sqrtf(fmaxf(1.f + gn2, EPSC));
  float gyn = fmaxf(sqrtf(gn2), MINN);
  float l = sp ? facoshp(fmaxf(g0, 1.f + EPSC)) * __fdividef(g, gyn) : 0.f;
  float t = fmaxf(l, 0.f);
  float rt = fmaxf(sqrtf(gsum8(t * t)), MINN);
  float sht = fsinh(rt);
  float h = sp ? sht * __fdividef(t, rt) : 0.f;
  float hn2 = gsum8(h * h);
  float h0 = sqrtf(fmaxf(1.f + hn2, EPSC));
  float hyn = fmaxf(sqrtf(hn2), MINN);
  return sp ? facoshp(fmaxf(h0, 1.f + EPSC)) * __fdividef(h, hyn) : 0.f;
}

// ===== prep: W1 fragments (0..91) + bias tangents (92) + cnt zero (93..288) ===
__global__ __launch_bounds__(256) void prep_wb_zero(const float* __restrict__ W1,
                                                    const float* __restrict__ b1,
                                                    const float* __restrict__ b2,
                                                    unsigned short* __restrict__ wfrag,
                                                    float* __restrict__ ub,
                                                    int* __restrict__ cnt) {
  if (blockIdx.x >= 93) {
    int i = (blockIdx.x - 93) * 256 + threadIdx.x;
    if (i < NN) cnt[i] = 0;
    return;
  }
  if (blockIdx.x == 92) {
    const int w = threadIdx.x >> 6, lane = threadIdx.x & 63;
    if (w == 0) ub[lane] = bias_tangent(b1, lane, 64);
    else if (w == 1) ub[64 + lane] = bias_tangent(b2, lane, 7);
    return;
  }
  int idx = blockIdx.x * 256 + threadIdx.x;
  int lane = idx & 63;
  int c = (idx >> 6) & 7;
  int rest = idx >> 9;
  int kt = rest % NKT;
  int half = rest / NKT;
  int type = c >> 2, nt = c & 3;
  int col = nt * 16 + (lane & 15);
  unsigned short vals[8];
#pragma unroll
  for (int i = 0; i < 8; ++i) {
    int lk = kt * 32 + (lane >> 4) * 8 + i;
    float wv = (lk < KHALF) ? W1[col * DIN + half * KHALF + lk + 1] : 0.f;
    unsigned int h16, l16;
    split_bf(wv, h16, l16);
    vals[i] = (unsigned short)((type == 0) ? h16 : l16);
  }
  unsigned short* dst = wfrag + (((size_t)(half * NKT + kt) * 8 + c) * 64 + lane) * 8;
#pragma unroll
  for (int i = 0; i < 8; ++i) dst[i] = vals[i];
}

// ===================== CSR mid-chain ==========================================
__global__ __launch_bounds__(256) void k_blocksum(const int* __restrict__ cnt,
                                                  int* __restrict__ bsum) {
  __shared__ int wpart[4];
  int i = blockIdx.x * 256 + threadIdx.x;
  int v = (i < NN) ? cnt[i] : 0;
  int s = v;
#pragma unroll
  for (int o = 1; o < 64; o <<= 1) s += __shfl_xor(s, o, 64);
  if ((threadIdx.x & 63) == 0) wpart[threadIdx.x >> 6] = s;
  __syncthreads();
  if (threadIdx.x == 0) bsum[blockIdx.x] = wpart[0] + wpart[1] + wpart[2] + wpart[3];
}

// scanb fused into apply (parallel redundant scan; validated R23)
__global__ __launch_bounds__(256) void k_scan_apply(const int* __restrict__ cnt,
                                                    const int* __restrict__ bsum,
                                                    int* __restrict__ rowptr,
                                                    int* __restrict__ cur) {
  __shared__ int s[256];
  __shared__ int base_sh;
  const int t = threadIdx.x;
  const int b = blockIdx.x;
  int bv = (t < NB) ? bsum[t] : 0;
  s[t] = bv;
  __syncthreads();
  for (int o = 1; o < 256; o <<= 1) {
    int a = (t >= o) ? s[t - o] : 0;
    __syncthreads();
    s[t] += a;
    __syncthreads();
  }
  if (t == b) base_sh = s[b] - bv;
  __syncthreads();
  const int base = base_sh;
  __syncthreads();
  int i = b * 256 + t;
  int v = (i < NN) ? cnt[i] : 0;
  s[t] = v;
  __syncthreads();
  for (int o = 1; o < 256; o <<= 1) {
    int a = (t >= o) ? s[t - o] : 0;
    __syncthreads();
    s[t] += a;
    __syncthreads();
  }
  int ex = s[t] - v + base;
  if (i < NN) { rowptr[i] = ex; cur[i] = ex; }
  if (i == NN - 1) rowptr[NN] = EE;
}

// ======== GEMM1 half: BM=128 + counted pipeline + hist plane (blockIdx.y==2) ==
// Bracket test: per-wave MFMA 24/iter, B L2 traffic halves vs BM=64; LDS 64KB
// -> 2 blocks/CU (the known cliff — counted vmcnt may tolerate it).
// Per-iter VMEM/wave: B(kt+1)x2 then A(kt+2)x4; wait vmcnt(4).
__global__ __launch_bounds__(256) void gemm_hist(const float* __restrict__ x,
                                                 const unsigned short* __restrict__ wfrag,
                                                 float* __restrict__ z,
                                                 const int* __restrict__ row,
                                                 int* __restrict__ cnt) {
  if (blockIdx.y == 2) {   // histogram plane: 391 blocks x 2048 edges
    int e = blockIdx.x * 2048 + threadIdx.x;
#pragma unroll
    for (int i = 0; i < 8; ++i) {
      if (e < EE) atomicAdd(&cnt[row[e]], 1);
      e += 256;
    }
    return;
  }
  __shared__ __align__(16) float XA[3 * 4096];               // 48 KB: 3x [128][32] f32
  __shared__ __align__(16) unsigned short BB[2][8][64][8];   // 16 KB
  const int tid = threadIdx.x;
  const int w = tid >> 6, lane = tid & 63;
  const int row0 = blockIdx.x * 128;
  const int half = blockIdx.y;
  const unsigned short* wf = wfrag + (size_t)half * NKT * 4096;
  float* zp = z + (size_t)half * 3200000;
  const int nt0 = (w >> 1) * 2;

  auto stageB = [&](int kt, int p) {
    const unsigned short* src = wf + (size_t)kt * 4096 + (2 * w) * 512 + lane * 8;
    __builtin_amdgcn_global_load_lds(
        (const __attribute__((address_space(1))) unsigned int*)src,
        (__attribute__((address_space(3))) unsigned int*)(&BB[p][2 * w][0][0]), 16, 0, 0);
    __builtin_amdgcn_global_load_lds(
        (const __attribute__((address_space(1))) unsigned int*)(src + 512),
        (__attribute__((address_space(3))) unsigned int*)(&BB[p][2 * w + 1][0][0]), 16, 0, 0);
  };
  // A tile [128][32] f32: wave w stages rows w*32..w*32+31 with 4x 16B gl_lds.
  auto stageA = [&](int kt, int q) {
#pragma unroll
    for (int i = 0; i < 4; ++i) {
      const int r = w * 32 + i * 8 + (lane >> 3);
      const int lb = (lane & 7) ^ (r & 7);          // source block pre-swizzle
      int grow = row0 + r; if (grow >= NN) grow = NN - 1;
      size_t off = (size_t)grow * DIN + 1 + half * KHALF + kt * 32 + lb * 4;
      if (off > (size_t)NN * DIN - 4) off = (size_t)NN * DIN - 4;   // tail clamp
      __builtin_amdgcn_global_load_lds(
          (const __attribute__((address_space(1))) unsigned int*)(x + off),
          (__attribute__((address_space(3))) unsigned int*)(XA + q * 4096 + w * 1024 + i * 256),
          16, 0, 0);
    }
  };

  f32x4 acc[4][2];
#pragma unroll
  for (int m = 0; m < 4; ++m)
#pragma unroll
    for (int n = 0; n < 2; ++n) acc[m][n] = (f32x4){0.f, 0.f, 0.f, 0.f};

  stageB(0, 0);
  stageA(0, 0);
  stageA(1, 1);
  __builtin_amdgcn_sched_barrier(0);
  asm volatile("s_waitcnt vmcnt(4)" ::: "memory");
  __builtin_amdgcn_s_barrier();
  __builtin_amdgcn_sched_barrier(0);

  const int rrb = (w & 1) * 64 + (lane & 15);   // row frag m: rrb + m*16
  const int b0 = (lane >> 4) * 2;

  for (int kt = 0; kt < NKT; ++kt) {
    if (kt + 1 < NKT) stageB(kt + 1, (kt + 1) & 1);
    if (kt + 2 < NKT) stageA(kt + 2, (kt + 2) % 3);
    const float* xaq = XA + (kt % 3) * 4096;
    bf16x8 ah[4], al[4];
#pragma unroll
    for (int m = 0; m < 4; ++m) {
      const int rr = rrb + m * 16;
      const float* xa = xaq + rr * 32;
      float4 f0 = *(const float4*)(xa + ((b0 ^ (rr & 7)) * 4));
      float4 f1 = *(const float4*)(xa + (((b0 + 1) ^ (rr & 7)) * 4));
      float af[8] = {f0.x, f0.y, f0.z, f0.w, f1.x, f1.y, f1.z, f1.w};
      unsigned int h[8], l[8];
#pragma unroll
      for (int j = 0; j < 8; ++j) split_bf(af[j], h[j], l[j]);
#pragma unroll
      for (int j = 0; j < 8; ++j) { ah[m][j] = (short)h[j]; al[m][j] = (short)l[j]; }
    }
    bf16x8 bh[2], bl[2];
#pragma unroll
    for (int n = 0; n < 2; ++n) {
      bh[n] = *(const bf16x8*)&BB[kt & 1][nt0 + n][lane][0];
      bl[n] = *(const bf16x8*)&BB[kt & 1][4 + nt0 + n][lane][0];
    }
    __builtin_amdgcn_s_setprio(1);
#pragma unroll
    for (int m = 0; m < 4; ++m)
#pragma unroll
      for (int n = 0; n < 2; ++n) {
        acc[m][n] = __builtin_amdgcn_mfma_f32_16x16x32_bf16(ah[m], bh[n], acc[m][n], 0, 0, 0);
        acc[m][n] = __builtin_amdgcn_mfma_f32_16x16x32_bf16(ah[m], bl[n], acc[m][n], 0, 0, 0);
        acc[m][n] = __builtin_amdgcn_mfma_f32_16x16x32_bf16(al[m], bh[n], acc[m][n], 0, 0, 0);
      }
    __builtin_amdgcn_s_setprio(0);
    if (kt + 1 < NKT) {
      __builtin_amdgcn_sched_barrier(0);
      asm volatile("s_waitcnt lgkmcnt(0)" ::: "memory");
      if (kt + 2 < NKT) asm volatile("s_waitcnt vmcnt(4)" ::: "memory");
      else              asm volatile("s_waitcnt vmcnt(0)" ::: "memory");
      __builtin_amdgcn_s_barrier();
      __builtin_amdgcn_sched_barrier(0);
    }
  }
  // epilogue: D row=(lane>>4)*4+i, col=lane&15
#pragma unroll
  for (int m = 0; m < 4; ++m)
#pragma unroll
    for (int n = 0; n < 2; ++n)
#pragma unroll
      for (int i = 0; i < 4; ++i) {
        int orow = row0 + (w & 1) * 64 + m * 16 + (lane >> 4) * 4 + i;
        int ocol = (nt0 + n) * 16 + (lane & 15);
        if (orow < NN) zp[(size_t)orow * 64 + ocol] = acc[m][n][i];
      }
}

// ===== node1 (blocks 0..12499) + scatter plane (blocks 12500..15624) ==========
__global__ __launch_bounds__(256) void node1_scatter(const float* __restrict__ z1a,
                                                     const float* __restrict__ z1b,
                                                     const float* __restrict__ ub,
                                                     unsigned short* __restrict__ xtb,
                                                     const int* __restrict__ row,
                                                     const int* __restrict__ col,
                                                     const float* __restrict__ ew,
                                                     int* __restrict__ cur,
                                                     uint2* __restrict__ ep) {
  if (blockIdx.x >= 12500) {   // scatter plane: 3125 blocks
    int e = (blockIdx.x - 12500) * 256 + threadIdx.x;
    if (e < EE) {
      int p = atomicAdd(&cur[row[e]], 1);
      uint2 q;
      q.x = (unsigned int)col[e];
      q.y = __float_as_uint(ew[e]);
      ep[p] = q;
    }
    return;
  }
  const int node = blockIdx.x * 4 + (threadIdx.x >> 6);
  const int lane = threadIdx.x & 63;
  const int idx = node * 64 + lane;
  float z = z1a[idx] + z1b[idx];
  float u1 = ub[lane];
  float o = chain_with_u(z, u1, lane, 64);
  xtb[idx] = f2bf_rne(o);
}

// ===== agg1 (bf16 gather, masked-tail unroll-8) + chains + W2 =================
__global__ __launch_bounds__(256) void agg1_node2(const int* __restrict__ rowptr,
                                                  const uint2* __restrict__ ep,
                                                  const unsigned short* __restrict__ xtb,
                                                  const float* __restrict__ W2,
                                                  const float* __restrict__ ub,
                                                  float* __restrict__ xt3) {
  const int node = blockIdx.x * 4 + (threadIdx.x >> 6);
  const int lane = threadIdx.x & 63;
  const int s0 = rowptr[node], s1 = rowptr[node + 1];
  float a0 = 0.f, a1 = 0.f, a2 = 0.f, a3 = 0.f;
  float a4 = 0.f, a5 = 0.f, a6 = 0.f, a7 = 0.f;
  for (int p = s0; p < s1; p += 8) {
    int p1 = min(p + 1, s1 - 1), p2 = min(p + 2, s1 - 1), p3 = min(p + 3, s1 - 1);
    int p4 = min(p + 4, s1 - 1), p5 = min(p + 5, s1 - 1), p6 = min(p + 6, s1 - 1), p7 = min(p + 7, s1 - 1);
    uint2 q0 = ep[p], q1 = ep[p1], q2 = ep[p2], q3 = ep[p3];
    uint2 q4 = ep[p4], q5 = ep[p5], q6 = ep[p6], q7 = ep[p7];
    float w0 = __uint_as_float(q0.y);
    float w1 = (p + 1 < s1) ? __uint_as_float(q1.y) : 0.f;
    float w2 = (p + 2 < s1) ? __uint_as_float(q2.y) : 0.f;
    float w3 = (p + 3 < s1) ? __uint_as_float(q3.y) : 0.f;
    float w4 = (p + 4 < s1) ? __uint_as_float(q4.y) : 0.f;
    float w5 = (p + 5 < s1) ? __uint_as_float(q5.y) : 0.f;
    float w6 = (p + 6 < s1) ? __uint_as_float(q6.y) : 0.f;
    float w7 = (p + 7 < s1) ? __uint_as_float(q7.y) : 0.f;
    a0 = fmaf(w0, bf2f(xtb[(size_t)q0.x * 64 + lane]), a0);
    a1 = fmaf(w1, bf2f(xtb[(size_t)q1.x * 64 + lane]), a1);
    a2 = fmaf(w2, bf2f(xtb[(size_t)q2.x * 64 + lane]), a2);
    a3 = fmaf(w3, bf2f(xtb[(size_t)q3.x * 64 + lane]), a3);
    a4 = fmaf(w4, bf2f(xtb[(size_t)q4.x * 64 + lane]), a4);
    a5 = fmaf(w5, bf2f(xtb[(size_t)q5.x * 64 + lane]), a5);
    a6 = fmaf(w6, bf2f(xtb[(size_t)q6.x * 64 + lane]), a6);
    a7 = fmaf(w7, bf2f(xtb[(size_t)q7.x * 64 + lane]), a7);
  }
  float acc = ((a0 + a1) + (a2 + a3)) + ((a4 + a5) + (a6 + a7));
  float xt2 = agg_act_chain(acc, lane, 64);
  float z2 = 0.f;
#pragma unroll
  for (int jj = 1; jj < 7; ++jj) {
    float wv = W2[jj * 64 + lane];
    float sjj = wsum(xt2 * wv);
    if (lane == jj) z2 = sjj;
  }
  float u2 = ub[64 + lane];
  float o = chain_with_u(z2, u2, lane, 7);
  if (lane < 8) xt3[node * 8 + lane] = o;
}

// ============== agg2 + final chain: 8 nodes/wave, masked-tail unroll-4 ========
__global__ __launch_bounds__(256) void agg2_final(const int* __restrict__ rowptr,
                                                  const uint2* __restrict__ ep,
                                                  const float* __restrict__ xt3,
                                                  float* __restrict__ out) {
  const int node = blockIdx.x * 32 + (threadIdx.x >> 3);
  const int f = threadIdx.x & 7;
  const int nc = (node < NN) ? node : (NN - 1);
  const int s0 = rowptr[nc], s1 = rowptr[nc + 1];
  float a0 = 0.f, a1 = 0.f, a2 = 0.f, a3 = 0.f;
  for (int p = s0; p < s1; p += 4) {
    int p1 = min(p + 1, s1 - 1), p2 = min(p + 2, s1 - 1), p3 = min(p + 3, s1 - 1);
    uint2 q0 = ep[p], q1 = ep[p1], q2 = ep[p2], q3 = ep[p3];
    float w0 = __uint_as_float(q0.y);
    float w1 = (p + 1 < s1) ? __uint_as_float(q1.y) : 0.f;
    float w2 = (p + 2 < s1) ? __uint_as_float(q2.y) : 0.f;
    float w3 = (p + 3 < s1) ? __uint_as_float(q3.y) : 0.f;
    a0 = fmaf(w0, xt3[(size_t)q0.x * 8 + f], a0);
    a1 = fmaf(w1, xt3[(size_t)q1.x * 8 + f], a1);
    a2 = fmaf(w2, xt3[(size_t)q2.x * 8 + f], a2);
    a3 = fmaf(w3, xt3[(size_t)q3.x * 8 + f], a3);
  }
  float acc = (a0 + a1) + (a2 + a3);
  float o = agg_act_chain8(acc, f);
  if (node < NN && f < 7) out[node * 7 + f] = o;
}

extern "C" void kernel_launch(void* const* d_in, const int* in_sizes, int n_in,
                              void* d_out, int out_size, void* d_ws, size_t ws_size,
                              hipStream_t stream) {
  const float* x = (const float*)d_in[0];
  const int* row = (const int*)d_in[1];
  const int* col = (const int*)d_in[2];
  const float* ew = (const float*)d_in[3];
  const float* W1 = (const float*)d_in[4];
  const float* b1 = (const float*)d_in[5];
  const float* W2 = (const float*)d_in[6];
  const float* b2 = (const float*)d_in[7];
  float* ws = (float*)d_ws;
  unsigned short* wfrag = (unsigned short*)(ws + WF_OFF);
  float* z1a = ws + Z1A_OFF;
  float* z1b = ws + Z1B_OFF;
  unsigned short* xtb = (unsigned short*)(ws + XTB_OFF);
  float* xt3 = ws + XT3_OFF;
  int* cnt = (int*)(ws + CNT_OFF);
  int* rowptr = (int*)(ws + ROWPTR_OFF);
  int* cur = (int*)(ws + CUR_OFF);
  int* bsum = (int*)(ws + BSUM_OFF);
  float* ub = ws + UB_OFF;
  uint2* ep = (uint2*)(ws + EP_OFF);
  float* out = (float*)d_out;

  // prep: W fragments + bias tangents + cnt zero (one launch)
  prep_wb_zero<<<dim3(289), dim3(256), 0, stream>>>(W1, b1, b2, wfrag, ub, cnt);

  // gemm BM=128 (y=0,1) + histogram plane (y=2)
  gemm_hist<<<dim3(391, 3), dim3(256), 0, stream>>>(x, wfrag, z1a, row, cnt);

  // CSR mid-chain: blocksum, then scan+apply fused
  k_blocksum<<<dim3(NB), dim3(256), 0, stream>>>(cnt, bsum);
  k_scan_apply<<<dim3(NB), dim3(256), 0, stream>>>(cnt, bsum, rowptr, cur);

  // node1 (0..12499) + scatter plane (12500..15624)
  node1_scatter<<<dim3(15625), dim3(256), 0, stream>>>(z1a, z1b, ub, xtb,
                                                       row, col, ew, cur, ep);

  agg1_node2<<<dim3(12500), dim3(256), 0, stream>>>(rowptr, ep, xtb, W2, ub, xt3);
  agg2_final<<<dim3(1563), dim3(256), 0, stream>>>(rowptr, ep, xt3, out);
}